// Round 5
// baseline (30887.723 us; speedup 1.0000x reference)
//
#include <hip/hip_runtime.h>

// DA-RNN persistent kernel, round 5: MFMA (16x16x32 f16) for all GEMV/GEMM
// phases with pre-swizzled B-fragment weights; BB=8 batch rows/block (M=16
// half-padded), 128 blocks x 512 thr, ~110KB dynamic LDS, VALU only for the
// tanh-identity score phases + LSTM pointwise. Zero grid syncs.

#define B_   1024
#define T_   128     // T_ENCO
#define NI_  128     // N_INP
#define H_   256     // N_HID
#define TD_  24      // T_DECO
#define DS_  30      // decoder steps
#define BB   8       // batch rows per workgroup
#define TB   512     // threads per block (8 waves)

typedef _Float16 hf_t;
typedef _Float16 h8  __attribute__((ext_vector_type(8)));
typedef _Float16 h2v __attribute__((ext_vector_type(2)));
typedef float    f4  __attribute__((ext_vector_type(4)));

__device__ __forceinline__ float sigm(float x) {
    return __builtin_amdgcn_rcpf(1.0f + __expf(-x));
}
__device__ __forceinline__ float tanh_f(float x) {
    float e = __expf(2.0f * x);
    return 1.0f - 2.0f * __builtin_amdgcn_rcpf(e + 1.0f);
}

// ---- f16 weight-fragment arrays in d_ws (offsets in halves) ----
// Frag layout: F[((nt*KI + ki)*64 + lane)*8 + e] = W[nt*16 + (lane&15)][ki*32 + (lane>>4)*8 + e]
#define W_WEF  0u         // [We(512)|Ue2(128)] rows 256, KI=20 -> 163840
#define W_EIF  163840u    // [eWih(128)|eWhh(256)] rows 1024, KI=12 -> 393216
#define W_MGF  557056u    // [mWih(256)|mWhh(256)] rows 1024, KI=16 -> 524288
#define W_DGF  1081344u   // [dWih(256)|dWhh(256)] rows 1024, KI=16 -> 524288
#define W_WDF  1605632u   // Wd rows 256 K=512, KI=16 -> 131072
#define W_UDF  1736704u   // Ud rows 256 K=256, KI=8  -> 65536
#define W_UEF  1802240u   // UeW rows 256 K=128, KI=4 -> 32768
#define SCR_A  2097152u   // Tu2 [b][kc32][j128][8] -> Td2 [b][oc32][t128][8]
#define SCR_B  35651584u  // mid [b][t][k] f16

// ---- LDS offsets (bytes) ----
#define L_ATT   0        // hf [16][648]  [h|c|x] stride 648
#define L_ENC   20736    // hf [16][392]  [xg|h]  stride 392
#define L_MID   33280    // hf [16][520]  [he|hm] / dec [din|h] stride 520
#define L_CFE   49920    // f32 [256][8]
#define L_CFM   58112    // f32 [256][8] ; decoder reuses as hful f32 [8][256]
#define L_VES   66304    // hf [256]
#define L_VDS   66816    // hf [256]
#define L_XH    67328    // hf [8][128]
#define L_SBUF  69376    // f32 [8][128]
#define L_TAH   73472    // hf [8][264]
#define L_GBUF  77824    // f32 [1024][8] (32768) U XT hf [128][136] (34816)
#define LDS_BYTES 112640

__global__ void convw_kernel(const float* __restrict__ sWE, const float* __restrict__ sUE2,
                             const float* __restrict__ sEI, const float* __restrict__ sEH,
                             const float* __restrict__ sMI, const float* __restrict__ sMH,
                             const float* __restrict__ sDI, const float* __restrict__ sDH,
                             const float* __restrict__ sWD, const float* __restrict__ sUD,
                             const float* __restrict__ sUE,
                             hf_t* __restrict__ dst) {
    const int gtid = blockIdx.x * blockDim.x + threadIdx.x;
    const int gs   = gridDim.x * blockDim.x;
    for (int n = gtid; n < 163840; n += gs) {            // WEF KI=20
        int e = n & 7, li = (n >> 3) & 63, fi = n >> 9;
        int ki = fi % 20, nt = fi / 20;
        int row = nt * 16 + (li & 15), k = ki * 32 + (li >> 4) * 8 + e;
        float v = (k < 512) ? sWE[row * 512 + k] : sUE2[row * 128 + (k - 512)];
        dst[W_WEF + n] = (hf_t)v;
    }
    for (int n = gtid; n < 393216; n += gs) {            // EIF KI=12
        int e = n & 7, li = (n >> 3) & 63, fi = n >> 9;
        int ki = fi % 12, nt = fi / 12;
        int row = nt * 16 + (li & 15), k = ki * 32 + (li >> 4) * 8 + e;
        float v = (k < 128) ? sEI[row * 128 + k] : sEH[row * 256 + (k - 128)];
        dst[W_EIF + n] = (hf_t)v;
    }
    for (int n = gtid; n < 524288; n += gs) {            // MGF + DGF KI=16
        int e = n & 7, li = (n >> 3) & 63, fi = n >> 9;
        int ki = fi & 15, nt = fi >> 4;
        int row = nt * 16 + (li & 15), k = ki * 32 + (li >> 4) * 8 + e;
        float vm = (k < 256) ? sMI[row * 256 + k] : sMH[row * 256 + (k - 256)];
        float vd = (k < 256) ? sDI[row * 256 + k] : sDH[row * 256 + (k - 256)];
        dst[W_MGF + n] = (hf_t)vm;
        dst[W_DGF + n] = (hf_t)vd;
    }
    for (int n = gtid; n < 131072; n += gs) {            // WDF KI=16
        int e = n & 7, li = (n >> 3) & 63, fi = n >> 9;
        int ki = fi & 15, nt = fi >> 4;
        int row = nt * 16 + (li & 15), k = ki * 32 + (li >> 4) * 8 + e;
        dst[W_WDF + n] = (hf_t)sWD[row * 512 + k];
    }
    for (int n = gtid; n < 65536; n += gs) {             // UDF KI=8
        int e = n & 7, li = (n >> 3) & 63, fi = n >> 9;
        int ki = fi & 7, nt = fi >> 3;
        int row = nt * 16 + (li & 15), k = ki * 32 + (li >> 4) * 8 + e;
        dst[W_UDF + n] = (hf_t)sUD[row * 256 + k];
    }
    for (int n = gtid; n < 32768; n += gs) {             // UEF KI=4
        int e = n & 7, li = (n >> 3) & 63, fi = n >> 9;
        int ki = fi & 3, nt = fi >> 2;
        int row = nt * 16 + (li & 15), k = ki * 32 + (li >> 4) * 8 + e;
        dst[W_UEF + n] = (hf_t)sUE[row * 128 + k];
    }
}

// gate GEMM: M=16(b-pad) x N=1024 x K=KI*32 -> gbuf[o][8] f32
template<int KI>
__device__ __forceinline__ void gemm_gates(const hf_t* __restrict__ wf,
        const hf_t* __restrict__ actA, int astride,
        float* __restrict__ gb, int tid) {
    const int lane = tid & 63, w = tid >> 6;
    const int m = lane & 15, q = lane >> 4;
    h8 A[KI];
#pragma unroll
    for (int ki = 0; ki < KI; ++ki)
        A[ki] = *(const h8*)(actA + m * astride + ki * 32 + q * 8);
    const h8* wv = (const h8*)wf;
#pragma unroll
    for (int np = 0; np < 4; ++np) {
        const int nt0 = w * 8 + np * 2;
        f4 a0 = {0.f, 0.f, 0.f, 0.f}, a1 = {0.f, 0.f, 0.f, 0.f};
#pragma unroll
        for (int ki = 0; ki < KI; ++ki) {
            a0 = __builtin_amdgcn_mfma_f32_16x16x32_f16(A[ki], wv[(size_t)(nt0 * KI + ki) * 64 + lane], a0, 0, 0, 0);
            a1 = __builtin_amdgcn_mfma_f32_16x16x32_f16(A[ki], wv[(size_t)((nt0 + 1) * KI + ki) * 64 + lane], a1, 0, 0, 0);
        }
        if (q < 2) {
            *(f4*)(gb + ((nt0 * 16 + m) * 8 + q * 4)) = a0;
            *(f4*)(gb + (((nt0 + 1) * 16 + m) * 8 + q * 4)) = a1;
        }
    }
}

// att GEMM: M=16(b-pad) x N=256 x K=KI*32 -> Tah[b][264] = tanh(acc + bias)
template<int KI>
__device__ __forceinline__ void gemm_att(const hf_t* __restrict__ wf,
        const hf_t* __restrict__ actA, int astride,
        const float* __restrict__ bA, const float* __restrict__ bB,
        hf_t* __restrict__ Tah, int tid) {
    const int lane = tid & 63, w = tid >> 6;
    const int m = lane & 15, q = lane >> 4;
    h8 A[KI];
#pragma unroll
    for (int ki = 0; ki < KI; ++ki)
        A[ki] = *(const h8*)(actA + m * astride + ki * 32 + q * 8);
    const h8* wv = (const h8*)wf;
#pragma unroll
    for (int np = 0; np < 2; ++np) {
        const int nt = w * 2 + np;
        f4 acc = {0.f, 0.f, 0.f, 0.f};
#pragma unroll
        for (int ki = 0; ki < KI; ++ki)
            acc = __builtin_amdgcn_mfma_f32_16x16x32_f16(A[ki], wv[(size_t)(nt * KI + ki) * 64 + lane], acc, 0, 0, 0);
        const int k = nt * 16 + m;
        float bv = bA[k] + (bB ? bB[k] : 0.f);
        if (q < 2) {
#pragma unroll
            for (int r = 0; r < 4; ++r)
                Tah[(q * 4 + r) * 264 + k] = (hf_t)tanh_f(acc[r] + bv);
        }
    }
}

__global__ __launch_bounds__(TB, 2) void dsrnn_kernel(
    const float* __restrict__ inp,
    const float* __restrict__ Ueb,
    const float* __restrict__ Ue2b,
    const float* __restrict__ Web,
    const float* __restrict__ VeW,  const float* __restrict__ Veb,
    const float* __restrict__ Udb,
    const float* __restrict__ Wdb,
    const float* __restrict__ VdW,  const float* __restrict__ Vdb,
    const float* __restrict__ ebih, const float* __restrict__ ebhh,
    const float* __restrict__ mbih, const float* __restrict__ mbhh,
    const float* __restrict__ dbih, const float* __restrict__ dbhh,
    const float* __restrict__ rW,   const float* __restrict__ rb,
    const hf_t* __restrict__ wb,
    hf_t* __restrict__ scrA, hf_t* __restrict__ scrB,
    float* __restrict__ out)
{
    extern __shared__ char smraw[];
    hf_t*  attA = (hf_t*)(smraw + L_ATT);
    hf_t*  encA = (hf_t*)(smraw + L_ENC);
    hf_t*  midA = (hf_t*)(smraw + L_MID);
    float* cfE  = (float*)(smraw + L_CFE);
    float* cfM  = (float*)(smraw + L_CFM);
    hf_t*  vesh = (hf_t*)(smraw + L_VES);
    hf_t*  vdsh = (hf_t*)(smraw + L_VDS);
    hf_t*  xh   = (hf_t*)(smraw + L_XH);
    float* sbuf = (float*)(smraw + L_SBUF);
    hf_t*  Tah  = (hf_t*)(smraw + L_TAH);
    float* gbuf = (float*)(smraw + L_GBUF);
    hf_t*  XT   = (hf_t*)(smraw + L_GBUF);

    const int tid  = threadIdx.x;
    const int b0   = blockIdx.x * BB;
    const int lane = tid & 63, w = tid >> 6;
    const int fm   = lane & 15, fq = lane >> 4;

    // init: zero act buffers (incl. pad rows 8..15) + c-state, stage Ve/Vd f16
    for (int i = tid; i < 10368; i += TB) attA[i] = (hf_t)0.f;
    for (int i = tid; i < 6272;  i += TB) encA[i] = (hf_t)0.f;
    for (int i = tid; i < 8320;  i += TB) midA[i] = (hf_t)0.f;
    for (int i = tid; i < 2048;  i += TB) { cfE[i] = 0.f; cfM[i] = 0.f; }
    if (tid < 256) { vesh[tid] = (hf_t)VeW[tid]; vdsh[tid] = (hf_t)VdW[tid]; }

    // ---------- Phase 0: Tu2[b][kc][j][e] = tanh(sum_t X[t,j]*UeW[k,t]+Ueb[k]) ----------
    {
        const h8* uef = (const h8*)(wb + W_UEF);
        for (int b = 0; b < BB; ++b) {
            __syncthreads();
            for (int i = tid; i < 16384; i += TB) {
                int t = i >> 7, j = i & 127;
                XT[j * 136 + t] = (hf_t)inp[((size_t)(b0 + b) * T_ + t) * NI_ + j];
            }
            __syncthreads();
            h8 A[4];
#pragma unroll
            for (int ki = 0; ki < 4; ++ki)
                A[ki] = *(const h8*)(XT + (w * 16 + fm) * 136 + ki * 32 + fq * 8);
            hf_t* tub = scrA + (size_t)(b0 + b) * 32768;
            for (int nt = 0; nt < 16; ++nt) {
                f4 acc = {0.f, 0.f, 0.f, 0.f};
#pragma unroll
                for (int ki = 0; ki < 4; ++ki)
                    acc = __builtin_amdgcn_mfma_f32_16x16x32_f16(A[ki], uef[(size_t)(nt * 4 + ki) * 64 + lane], acc, 0, 0, 0);
                const int o = nt * 16 + fm;
                const float bv = Ueb[o];
#pragma unroll
                for (int r = 0; r < 4; ++r) {
                    int j = w * 16 + fq * 4 + r;
                    tub[((o >> 3) * 128 + j) * 8 + (o & 7)] = (hf_t)tanh_f(acc[r] + bv);
                }
            }
        }
    }
    __syncthreads();

    const float Veb0 = Veb[0];
    // ---------- Fused encoder + mid loop ----------
    for (int t = 0; t < T_; ++t) {
        // (a) stage x_t
        for (int i = tid; i < 1024; i += TB) {
            int b = i >> 7, j = i & 127;
            float v = inp[((size_t)(b0 + b) * T_ + t) * NI_ + j];
            xh[i] = (hf_t)v;
            attA[b * 648 + 512 + j] = (hf_t)v;
        }
        __syncthreads();
        // (b) att GEMM -> Tah = tanh(We.[h;c] + Ue2.x + biases)
        gemm_att<20>(wb + W_WEF, attA, 648, Web, Ue2b, Tah, tid);
        __syncthreads();
        // (c) scores via tanh identity
        {
            const int j = tid & 127, bq = tid >> 7;
#pragma unroll
            for (int bi = 0; bi < 2; ++bi) {
                const int b = bq * 2 + bi;
                const h8* up = (const h8*)(scrA + (size_t)(b0 + b) * 32768 + (size_t)j * 8);
                float acc = 0.f;
                for (int kc = 0; kc < 32; ++kc) {
                    h8 u  = up[(size_t)kc * 128];
                    h8 ta = *(const h8*)(Tah + b * 264 + kc * 8);
                    h8 ve = *(const h8*)(vesh + kc * 8);
#pragma unroll
                    for (int e = 0; e < 8; ++e) {
                        float tu = (float)u[e], taf = (float)ta[e];
                        acc = fmaf((float)ve[e] * (taf + tu),
                                   __builtin_amdgcn_rcpf(fmaf(taf, tu, 1.f)), acc);
                    }
                }
                sbuf[b * 128 + j] = acc + Veb0;
            }
        }
        __syncthreads();
        // (d) softmax per b (wave w <-> b=w), gate x -> encA[b][0..128)
        {
            const int b = w;
            float s0 = sbuf[b * 128 + lane], s1 = sbuf[b * 128 + 64 + lane];
            float mx = fmaxf(s0, s1);
            for (int d = 1; d < 64; d <<= 1) mx = fmaxf(mx, __shfl_xor(mx, d));
            float e0 = __expf(s0 - mx), e1 = __expf(s1 - mx);
            float ss = e0 + e1;
            for (int d = 1; d < 64; d <<= 1) ss += __shfl_xor(ss, d);
            float inv = 1.f / ss;
            encA[b * 392 + lane]      = (hf_t)((float)xh[b * 128 + lane] * e0 * inv);
            encA[b * 392 + 64 + lane] = (hf_t)((float)xh[b * 128 + 64 + lane] * e1 * inv);
        }
        __syncthreads();
        // (e) enc gates
        gemm_gates<12>(wb + W_EIF, encA, 392, gbuf, tid);
        __syncthreads();
        // (f) enc LSTM
#pragma unroll
        for (int p = 0; p < 4; ++p) {
            int idx = p * TB + tid;
            int b = idx & 7, k = idx >> 3;
            float gi = gbuf[k * 8 + b]         + ebih[k]       + ebhh[k];
            float gf = gbuf[(256 + k) * 8 + b] + ebih[256 + k] + ebhh[256 + k];
            float gg = gbuf[(512 + k) * 8 + b] + ebih[512 + k] + ebhh[512 + k];
            float go = gbuf[(768 + k) * 8 + b] + ebih[768 + k] + ebhh[768 + k];
            float c2 = sigm(gf) * cfE[k * 8 + b] + sigm(gi) * tanh_f(gg);
            float h2 = sigm(go) * tanh_f(c2);
            cfE[k * 8 + b] = c2;
            attA[b * 648 + k]       = (hf_t)h2;
            attA[b * 648 + 256 + k] = (hf_t)c2;
            encA[b * 392 + 128 + k] = (hf_t)h2;
            midA[b * 520 + k]       = (hf_t)h2;
        }
        __syncthreads();
        // (g) mid gates
        gemm_gates<16>(wb + W_MGF, midA, 520, gbuf, tid);
        __syncthreads();
        // (h) mid LSTM + store mid
#pragma unroll
        for (int p = 0; p < 4; ++p) {
            int idx = p * TB + tid;
            int b = idx & 7, k = idx >> 3;
            float gi = gbuf[k * 8 + b]         + mbih[k]       + mbhh[k];
            float gf = gbuf[(256 + k) * 8 + b] + mbih[256 + k] + mbhh[256 + k];
            float gg = gbuf[(512 + k) * 8 + b] + mbih[512 + k] + mbhh[512 + k];
            float go = gbuf[(768 + k) * 8 + b] + mbih[768 + k] + mbhh[768 + k];
            float c2 = sigm(gf) * cfM[k * 8 + b] + sigm(gi) * tanh_f(gg);
            float h2 = sigm(go) * tanh_f(c2);
            cfM[k * 8 + b] = c2;
            midA[b * 520 + 256 + k] = (hf_t)h2;
            scrB[((size_t)(b0 + b) * T_ + t) * H_ + k] = (hf_t)h2;
        }
        __syncthreads();
    }

    // ---------- Td pass: Td2[b][oc][t][e] = tanh(Ud.mid[b,t] + Udb) ----------
    {
        const h8* udf = (const h8*)(wb + W_UDF);
        for (int mi = 0; mi < 8; ++mi) {
            const int mt = w * 8 + mi;                       // 64 M-tiles of (b,t) rows
            const size_t arow = ((size_t)b0 * T_ + mt * 16 + fm) * H_;
            h8 A[8];
#pragma unroll
            for (int ki = 0; ki < 8; ++ki)
                A[ki] = *(const h8*)(scrB + arow + ki * 32 + fq * 8);
            for (int nt = 0; nt < 16; ++nt) {
                f4 acc = {0.f, 0.f, 0.f, 0.f};
#pragma unroll
                for (int ki = 0; ki < 8; ++ki)
                    acc = __builtin_amdgcn_mfma_f32_16x16x32_f16(A[ki], udf[(size_t)(nt * 8 + ki) * 64 + lane], acc, 0, 0, 0);
                const int o = nt * 16 + fm;
                const float bv = Udb[o];
#pragma unroll
                for (int r = 0; r < 4; ++r) {
                    int row = mt * 16 + fq * 4 + r;
                    int bb = row >> 7, tt = row & 127;
                    scrA[(size_t)(b0 + bb) * 32768 + ((o >> 3) * 128 + tt) * 8 + (o & 7)]
                        = (hf_t)tanh_f(acc[r] + bv);
                }
            }
        }
    }
    __syncthreads();
    // zero decoder state: attA [h|c], cfE, midA
    for (int i = tid; i < 8192; i += TB) attA[(i >> 9) * 648 + (i & 511)] = (hf_t)0.f;
    for (int i = tid; i < 2048; i += TB) cfE[i] = 0.f;
    for (int i = tid; i < 8320; i += TB) midA[i] = (hf_t)0.f;
    __syncthreads();

    const float Vdb0 = Vdb[0];
    const float rb0  = rb[0];
    // ---------- Decoder ----------
    for (int s = 0; s < DS_; ++s) {
        // (a2) Wd GEMM -> Tah
        gemm_att<16>(wb + W_WDF, attA, 648, Wdb, nullptr, Tah, tid);
        __syncthreads();
        // (b2) temporal scores (no softmax)
        {
            const int j = tid & 127, bq = tid >> 7;
#pragma unroll
            for (int bi = 0; bi < 2; ++bi) {
                const int b = bq * 2 + bi;
                const h8* up = (const h8*)(scrA + (size_t)(b0 + b) * 32768 + (size_t)j * 8);
                float acc = 0.f;
                for (int kc = 0; kc < 32; ++kc) {
                    h8 u  = up[(size_t)kc * 128];
                    h8 ta = *(const h8*)(Tah + b * 264 + kc * 8);
                    h8 ve = *(const h8*)(vdsh + kc * 8);
#pragma unroll
                    for (int e = 0; e < 8; ++e) {
                        float tu = (float)u[e], taf = (float)ta[e];
                        acc = fmaf((float)ve[e] * (taf + tu),
                                   __builtin_amdgcn_rcpf(fmaf(taf, tu, 1.f)), acc);
                    }
                }
                sbuf[b * 128 + j] = acc + Vdb0;
            }
        }
        __syncthreads();
        // (c2) dec_in[b,h] = sum_j t[b,j]*mid[b,j,h] -> midA[b][0..256)
        {
            const int h2i = tid & 127, bh = tid >> 7;
#pragma unroll
            for (int bi = 0; bi < 2; ++bi) {
                const int b = bh * 2 + bi;
                const hf_t* mp = scrB + (size_t)(b0 + b) * T_ * H_ + h2i * 2;
                float a0 = 0.f, a1 = 0.f;
                for (int j = 0; j < T_; ++j) {
                    h2v mv = *(const h2v*)(mp + (size_t)j * H_);
                    float wj = sbuf[b * 128 + j];
                    a0 = fmaf(wj, (float)mv.x, a0);
                    a1 = fmaf(wj, (float)mv.y, a1);
                }
                midA[b * 520 + h2i * 2]     = (hf_t)a0;
                midA[b * 520 + h2i * 2 + 1] = (hf_t)a1;
            }
        }
        __syncthreads();
        // (d2) dec gates
        gemm_gates<16>(wb + W_DGF, midA, 520, gbuf, tid);
        __syncthreads();
        // (e2) dec LSTM (hful in cfM region)
#pragma unroll
        for (int p = 0; p < 4; ++p) {
            int idx = p * TB + tid;
            int b = idx & 7, k = idx >> 3;
            float gi = gbuf[k * 8 + b]         + dbih[k]       + dbhh[k];
            float gf = gbuf[(256 + k) * 8 + b] + dbih[256 + k] + dbhh[256 + k];
            float gg = gbuf[(512 + k) * 8 + b] + dbih[512 + k] + dbhh[512 + k];
            float go = gbuf[(768 + k) * 8 + b] + dbih[768 + k] + dbhh[768 + k];
            float c2 = sigm(gf) * cfE[k * 8 + b] + sigm(gi) * tanh_f(gg);
            float h2 = sigm(go) * tanh_f(c2);
            cfE[k * 8 + b] = c2;
            attA[b * 648 + k]       = (hf_t)h2;
            attA[b * 648 + 256 + k] = (hf_t)c2;
            midA[b * 520 + 256 + k] = (hf_t)h2;
            cfM[b * 256 + k] = h2;                 // hful [b][k]
        }
        __syncthreads();
        // (f2) out[b, s-6] = rW.h + rb
        if (s >= 6 && tid < 256) {
            const int b = tid >> 5, l = tid & 31;
            float p = 0.f;
#pragma unroll
            for (int i = 0; i < 8; ++i)
                p = fmaf(rW[l + i * 32], cfM[b * 256 + l + i * 32], p);
            for (int d = 1; d < 32; d <<= 1) p += __shfl_xor(p, d);
            if (l == 0) out[(size_t)(b0 + b) * TD_ + (s - 6)] = p + rb0;
        }
        __syncthreads();
    }
}

extern "C" void kernel_launch(void* const* d_in, const int* in_sizes, int n_in,
                              void* d_out, int out_size, void* d_ws, size_t ws_size,
                              hipStream_t stream) {
    const float* inp  = (const float*)d_in[0];
    const float* UeW  = (const float*)d_in[2];
    const float* Ueb  = (const float*)d_in[3];
    const float* Ue2W = (const float*)d_in[4];
    const float* Ue2b = (const float*)d_in[5];
    const float* WeW  = (const float*)d_in[6];
    const float* Web  = (const float*)d_in[7];
    const float* VeW  = (const float*)d_in[8];
    const float* Veb  = (const float*)d_in[9];
    const float* UdW  = (const float*)d_in[10];
    const float* Udb  = (const float*)d_in[11];
    const float* WdW  = (const float*)d_in[12];
    const float* Wdb  = (const float*)d_in[13];
    const float* VdW  = (const float*)d_in[14];
    const float* Vdb  = (const float*)d_in[15];
    const float* eWih = (const float*)d_in[16];
    const float* eWhh = (const float*)d_in[17];
    const float* ebih = (const float*)d_in[18];
    const float* ebhh = (const float*)d_in[19];
    const float* mWih = (const float*)d_in[20];
    const float* mWhh = (const float*)d_in[21];
    const float* mbih = (const float*)d_in[22];
    const float* mbhh = (const float*)d_in[23];
    const float* dWih = (const float*)d_in[24];
    const float* dWhh = (const float*)d_in[25];
    const float* dbih = (const float*)d_in[26];
    const float* dbhh = (const float*)d_in[27];
    const float* rW   = (const float*)d_in[28];
    const float* rb   = (const float*)d_in[29];

    hf_t* wsb  = (hf_t*)d_ws;
    hf_t* scrA = wsb + SCR_A;
    hf_t* scrB = wsb + SCR_B;

    hipFuncSetAttribute((const void*)dsrnn_kernel,
                        hipFuncAttributeMaxDynamicSharedMemorySize, LDS_BYTES);

    convw_kernel<<<512, 256, 0, stream>>>(WeW, Ue2W, eWih, eWhh, mWih, mWhh,
                                          dWih, dWhh, WdW, UdW, UeW, wsb);

    dsrnn_kernel<<<B_ / BB, TB, LDS_BYTES, stream>>>(
        inp, Ueb, Ue2b, Web, VeW, Veb, Udb, Wdb, VdW, Vdb,
        ebih, ebhh, mbih, mbhh, dbih, dbhh, rW, rb,
        wsb, scrA, scrB, (float*)d_out);
}

// Round 6
// 20860.349 us; speedup vs baseline: 1.4807x; 1.4807x over previous
//
#include <hip/hip_runtime.h>

// DA-RNN persistent kernel, round 6: MFMA (16x16x32 f16) everywhere, BB=4 so
// grid=256 blocks (full chip, 1/CU) x 1024 threads (16 waves/CU). Weight
// fragments pre-swizzled in d_ws (validated in R5); A-fragments reloaded from
// LDS per tile to keep VGPR<=128. Zero grid syncs (batch-partitioned).

#define B_   1024
#define T_   128     // T_ENCO
#define NI_  128     // N_INP
#define H_   256     // N_HID
#define TD_  24      // T_DECO
#define DS_  30      // decoder steps
#define BB   4       // batch rows per workgroup
#define TB   1024    // threads per block (16 waves)

typedef _Float16 hf_t;
typedef _Float16 h8  __attribute__((ext_vector_type(8)));
typedef float    f4  __attribute__((ext_vector_type(4)));

__device__ __forceinline__ float sigm(float x) {
    return __builtin_amdgcn_rcpf(1.0f + __expf(-x));
}
__device__ __forceinline__ float tanh_f(float x) {
    float e = __expf(2.0f * x);
    return 1.0f - 2.0f * __builtin_amdgcn_rcpf(e + 1.0f);
}

// ---- f16 weight-fragment arrays in d_ws (offsets in halves) ----
// Frag layout (R5-validated):
// F[((nt*KI + ki)*64 + lane)*8 + e] = W[nt*16 + (lane&15)][ki*32 + (lane>>4)*8 + e]
#define W_WEF  0u         // [We(512)|Ue2(128)] rows 256, KI=20
#define W_EIF  163840u    // [eWih(128)|eWhh(256)] rows 1024, KI=12
#define W_MGF  557056u    // [mWih(256)|mWhh(256)] rows 1024, KI=16
#define W_DGF  1081344u   // [dWih(256)|dWhh(256)] rows 1024, KI=16
#define W_WDF  1605632u   // Wd rows 256 K=512, KI=16
#define W_UDF  1736704u   // Ud rows 256 K=256, KI=8
#define W_UEF  1802240u   // UeW rows 256 K=128, KI=4
#define SCR_A  2097152u   // Tu2 [b][kc32][j128][8] -> Td2 [b][oc32][t128][8]
#define SCR_B  35651584u  // mid [b][t][k] f16

__global__ void convw_kernel(const float* __restrict__ sWE, const float* __restrict__ sUE2,
                             const float* __restrict__ sEI, const float* __restrict__ sEH,
                             const float* __restrict__ sMI, const float* __restrict__ sMH,
                             const float* __restrict__ sDI, const float* __restrict__ sDH,
                             const float* __restrict__ sWD, const float* __restrict__ sUD,
                             const float* __restrict__ sUE,
                             hf_t* __restrict__ dst) {
    const int gtid = blockIdx.x * blockDim.x + threadIdx.x;
    const int gs   = gridDim.x * blockDim.x;
    for (int n = gtid; n < 163840; n += gs) {            // WEF KI=20
        int e = n & 7, li = (n >> 3) & 63, fi = n >> 9;
        int ki = fi % 20, nt = fi / 20;
        int row = nt * 16 + (li & 15), k = ki * 32 + (li >> 4) * 8 + e;
        float v = (k < 512) ? sWE[row * 512 + k] : sUE2[row * 128 + (k - 512)];
        dst[W_WEF + n] = (hf_t)v;
    }
    for (int n = gtid; n < 393216; n += gs) {            // EIF KI=12
        int e = n & 7, li = (n >> 3) & 63, fi = n >> 9;
        int ki = fi % 12, nt = fi / 12;
        int row = nt * 16 + (li & 15), k = ki * 32 + (li >> 4) * 8 + e;
        float v = (k < 128) ? sEI[row * 128 + k] : sEH[row * 256 + (k - 128)];
        dst[W_EIF + n] = (hf_t)v;
    }
    for (int n = gtid; n < 524288; n += gs) {            // MGF + DGF KI=16
        int e = n & 7, li = (n >> 3) & 63, fi = n >> 9;
        int ki = fi & 15, nt = fi >> 4;
        int row = nt * 16 + (li & 15), k = ki * 32 + (li >> 4) * 8 + e;
        float vm = (k < 256) ? sMI[row * 256 + k] : sMH[row * 256 + (k - 256)];
        float vd = (k < 256) ? sDI[row * 256 + k] : sDH[row * 256 + (k - 256)];
        dst[W_MGF + n] = (hf_t)vm;
        dst[W_DGF + n] = (hf_t)vd;
    }
    for (int n = gtid; n < 131072; n += gs) {            // WDF KI=16
        int e = n & 7, li = (n >> 3) & 63, fi = n >> 9;
        int ki = fi & 15, nt = fi >> 4;
        int row = nt * 16 + (li & 15), k = ki * 32 + (li >> 4) * 8 + e;
        dst[W_WDF + n] = (hf_t)sWD[row * 512 + k];
    }
    for (int n = gtid; n < 65536; n += gs) {             // UDF KI=8
        int e = n & 7, li = (n >> 3) & 63, fi = n >> 9;
        int ki = fi & 7, nt = fi >> 3;
        int row = nt * 16 + (li & 15), k = ki * 32 + (li >> 4) * 8 + e;
        dst[W_UDF + n] = (hf_t)sUD[row * 256 + k];
    }
    for (int n = gtid; n < 32768; n += gs) {             // UEF KI=4
        int e = n & 7, li = (n >> 3) & 63, fi = n >> 9;
        int ki = fi & 3, nt = fi >> 2;
        int row = nt * 16 + (li & 15), k = ki * 32 + (li >> 4) * 8 + e;
        dst[W_UEF + n] = (hf_t)sUE[row * 128 + k];
    }
}

// ---- LDS offsets (bytes); act strides = 8 mod 16 halves (16B rows, 2-way banks) ----
#define L_ATT   0        // hf [16][648]  [h(256)|c(256)|x(128)]
#define L_ENC   20736    // hf [16][392]  [xg(128)|h(256)]
#define L_MID   33280    // hf [16][520]  [he|hm] / dec [din|h]
#define L_CFE   49920    // f32 [256][4]
#define L_CFM   54016    // f32 [256][4] ; decoder reuses as hful f32 [4][256]
#define L_VES   58112    // hf [256]
#define L_VDS   58624    // hf [256]
#define L_XH    59136    // hf [4][128]
#define L_SPART 60160    // f32 [1024]
#define L_SBUF  64256    // f32 [4][128]
#define L_TAH   66304    // hf [4][264]
#define L_GBUF  68416    // f32 [1024][4] (16384) U XT hf [128][136] (34816)
#define LDS_BYTES 103232

__global__ __launch_bounds__(TB) void dsrnn_kernel(
    const float* __restrict__ inp,
    const float* __restrict__ Ueb,
    const float* __restrict__ Ue2b,
    const float* __restrict__ Web,
    const float* __restrict__ VeW,  const float* __restrict__ Veb,
    const float* __restrict__ Udb,
    const float* __restrict__ Wdb,
    const float* __restrict__ VdW,  const float* __restrict__ Vdb,
    const float* __restrict__ ebih, const float* __restrict__ ebhh,
    const float* __restrict__ mbih, const float* __restrict__ mbhh,
    const float* __restrict__ dbih, const float* __restrict__ dbhh,
    const float* __restrict__ rW,   const float* __restrict__ rb,
    const hf_t* __restrict__ wb,
    hf_t* __restrict__ scrA, hf_t* __restrict__ scrB,
    float* __restrict__ out)
{
    extern __shared__ char smraw[];
    hf_t*  attA = (hf_t*)(smraw + L_ATT);
    hf_t*  encA = (hf_t*)(smraw + L_ENC);
    hf_t*  midA = (hf_t*)(smraw + L_MID);
    float* cfE  = (float*)(smraw + L_CFE);
    float* cfM  = (float*)(smraw + L_CFM);
    hf_t*  vesh = (hf_t*)(smraw + L_VES);
    hf_t*  vdsh = (hf_t*)(smraw + L_VDS);
    hf_t*  xh   = (hf_t*)(smraw + L_XH);
    float* spart= (float*)(smraw + L_SPART);
    float* sbuf = (float*)(smraw + L_SBUF);
    hf_t*  Tah  = (hf_t*)(smraw + L_TAH);
    float* gbuf = (float*)(smraw + L_GBUF);
    hf_t*  XT   = (hf_t*)(smraw + L_GBUF);

    const int tid  = threadIdx.x;
    const int b0   = blockIdx.x * BB;
    const int lane = tid & 63, w = tid >> 6;      // 16 waves
    const int fm   = lane & 15, fq = lane >> 4;

    // init: zero act buffers (incl. pad rows) + c-states; stage Ve/Vd
    for (int i = tid; i < 10368; i += TB) attA[i] = (hf_t)0.f;
    for (int i = tid; i < 6272;  i += TB) encA[i] = (hf_t)0.f;
    for (int i = tid; i < 8320;  i += TB) midA[i] = (hf_t)0.f;
    for (int i = tid; i < 1024;  i += TB) { cfE[i] = 0.f; cfM[i] = 0.f; }
    if (tid < 256) { vesh[tid] = (hf_t)VeW[tid]; vdsh[tid] = (hf_t)VdW[tid]; }

    // ---------- Phase 0: Tu2[b][kc][j][e] = tanh(sum_t X[t,j]*UeW[k,t]+Ueb[k]) ----------
    {
        const h8* uef = (const h8*)(wb + W_UEF);
        for (int b = 0; b < BB; ++b) {
            __syncthreads();
            for (int i = tid; i < 16384; i += TB) {
                int t0 = i >> 7, j = i & 127;
                XT[j * 136 + t0] = (hf_t)inp[((size_t)(b0 + b) * T_ + t0) * NI_ + j];
            }
            __syncthreads();
            const int mt = w & 7, ng = w >> 3;
            h8 A[4];
#pragma unroll
            for (int ki = 0; ki < 4; ++ki)
                A[ki] = *(const h8*)(XT + (mt * 16 + fm) * 136 + ki * 32 + fq * 8);
            hf_t* tub = scrA + (size_t)(b0 + b) * 32768;
            for (int p = 0; p < 8; ++p) {
                const int nt = ng * 8 + p;
                f4 acc = {0.f, 0.f, 0.f, 0.f};
#pragma unroll
                for (int ki = 0; ki < 4; ++ki)
                    acc = __builtin_amdgcn_mfma_f32_16x16x32_f16(A[ki], uef[(size_t)(nt * 4 + ki) * 64 + lane], acc, 0, 0, 0);
                const int o = nt * 16 + fm;
                const float bv = Ueb[o];
#pragma unroll
                for (int r = 0; r < 4; ++r) {
                    int j = mt * 16 + fq * 4 + r;
                    tub[((o >> 3) * 128 + j) * 8 + (o & 7)] = (hf_t)tanh_f(acc[r] + bv);
                }
            }
        }
    }
    __syncthreads();

    // ---------- Fused encoder + mid loop ----------
    for (int t = 0; t < T_; ++t) {
        // (a) stage x_t
        if (tid < 512) {
            int b = tid >> 7, j = tid & 127;
            float v = inp[((size_t)(b0 + b) * T_ + t) * NI_ + j];
            xh[b * 128 + j] = (hf_t)v;
            attA[b * 648 + 512 + j] = (hf_t)v;
        }
        __syncthreads();
        // (b) att GEMM: Tah = tanh(We.[h;c] + Ue2.x + biases)
        {
            const int nt = w;
            const h8* wv = (const h8*)(wb + W_WEF);
            f4 acc = {0.f, 0.f, 0.f, 0.f};
#pragma unroll
            for (int ki = 0; ki < 20; ++ki) {
                h8 Af = *(const h8*)(attA + fm * 648 + ki * 32 + fq * 8);
                acc = __builtin_amdgcn_mfma_f32_16x16x32_f16(Af, wv[(size_t)(nt * 20 + ki) * 64 + lane], acc, 0, 0, 0);
            }
            if (fq == 0) {
                const int k = nt * 16 + fm;
                float bv = Web[k] + Ue2b[k];
#pragma unroll
                for (int r = 0; r < 4; ++r)
                    Tah[r * 264 + k] = (hf_t)tanh_f(acc[r] + bv);
            }
        }
        __syncthreads();
        // (c) scores via tanh identity (k-half split)
        {
            const int b = tid >> 8, r = tid & 255, kh = r >> 7, j = r & 127;
            const h8* up = (const h8*)(scrA + (size_t)(b0 + b) * 32768 + (size_t)kh * 16384 + (size_t)j * 8);
            float acc = 0.f;
#pragma unroll 4
            for (int i = 0; i < 16; ++i) {
                h8 u  = up[(size_t)i * 128];
                h8 ta = *(const h8*)(Tah + b * 264 + (kh * 16 + i) * 8);
                h8 ve = *(const h8*)(vesh + (kh * 16 + i) * 8);
#pragma unroll
                for (int e = 0; e < 8; ++e) {
                    float tu = (float)u[e], taf = (float)ta[e];
                    acc = fmaf((float)ve[e] * (taf + tu),
                               __builtin_amdgcn_rcpf(fmaf(taf, tu, 1.f)), acc);
                }
            }
            spart[tid] = acc;
        }
        __syncthreads();
        // (d) softmax per b (wave w<4 <-> b=w), gate x -> encA xg
        if (w < 4) {
            const int b = w;
            float s0 = spart[b * 256 + lane]      + spart[b * 256 + 128 + lane];
            float s1 = spart[b * 256 + 64 + lane] + spart[b * 256 + 192 + lane];
            float mx = fmaxf(s0, s1);
            for (int d = 1; d < 64; d <<= 1) mx = fmaxf(mx, __shfl_xor(mx, d));
            float e0 = __expf(s0 - mx), e1 = __expf(s1 - mx);
            float ss = e0 + e1;
            for (int d = 1; d < 64; d <<= 1) ss += __shfl_xor(ss, d);
            float inv = 1.f / ss;
            encA[b * 392 + lane]      = (hf_t)((float)xh[b * 128 + lane] * e0 * inv);
            encA[b * 392 + 64 + lane] = (hf_t)((float)xh[b * 128 + 64 + lane] * e1 * inv);
        }
        __syncthreads();
        // (e) enc gates -> gbuf[o][4]
        {
            const h8* wv = (const h8*)(wb + W_EIF);
#pragma unroll
            for (int np = 0; np < 4; ++np) {
                const int nt = w * 4 + np;
                f4 acc = {0.f, 0.f, 0.f, 0.f};
#pragma unroll
                for (int ki = 0; ki < 12; ++ki) {
                    h8 Af = *(const h8*)(encA + fm * 392 + ki * 32 + fq * 8);
                    acc = __builtin_amdgcn_mfma_f32_16x16x32_f16(Af, wv[(size_t)(nt * 12 + ki) * 64 + lane], acc, 0, 0, 0);
                }
                if (fq == 0) *(f4*)(gbuf + (nt * 16 + fm) * 4) = acc;
            }
        }
        __syncthreads();
        // (f) enc LSTM
        {
            const int b = tid >> 8, k = tid & 255;
            float gi = gbuf[k * 4 + b]           + ebih[k]       + ebhh[k];
            float gf = gbuf[(256 + k) * 4 + b]   + ebih[256 + k] + ebhh[256 + k];
            float gg = gbuf[(512 + k) * 4 + b]   + ebih[512 + k] + ebhh[512 + k];
            float go = gbuf[(768 + k) * 4 + b]   + ebih[768 + k] + ebhh[768 + k];
            float c2 = sigm(gf) * cfE[k * 4 + b] + sigm(gi) * tanh_f(gg);
            float h2 = sigm(go) * tanh_f(c2);
            cfE[k * 4 + b] = c2;
            attA[b * 648 + k]       = (hf_t)h2;
            attA[b * 648 + 256 + k] = (hf_t)c2;
            encA[b * 392 + 128 + k] = (hf_t)h2;
            midA[b * 520 + k]       = (hf_t)h2;
        }
        __syncthreads();
        // (g) mid gates
        {
            const h8* wv = (const h8*)(wb + W_MGF);
#pragma unroll
            for (int np = 0; np < 4; ++np) {
                const int nt = w * 4 + np;
                f4 acc = {0.f, 0.f, 0.f, 0.f};
#pragma unroll
                for (int ki = 0; ki < 16; ++ki) {
                    h8 Af = *(const h8*)(midA + fm * 520 + ki * 32 + fq * 8);
                    acc = __builtin_amdgcn_mfma_f32_16x16x32_f16(Af, wv[(size_t)(nt * 16 + ki) * 64 + lane], acc, 0, 0, 0);
                }
                if (fq == 0) *(f4*)(gbuf + (nt * 16 + fm) * 4) = acc;
            }
        }
        __syncthreads();
        // (h) mid LSTM + store mid
        {
            const int b = tid >> 8, k = tid & 255;
            float gi = gbuf[k * 4 + b]           + mbih[k]       + mbhh[k];
            float gf = gbuf[(256 + k) * 4 + b]   + mbih[256 + k] + mbhh[256 + k];
            float gg = gbuf[(512 + k) * 4 + b]   + mbih[512 + k] + mbhh[512 + k];
            float go = gbuf[(768 + k) * 4 + b]   + mbih[768 + k] + mbhh[768 + k];
            float c2 = sigm(gf) * cfM[k * 4 + b] + sigm(gi) * tanh_f(gg);
            float h2 = sigm(go) * tanh_f(c2);
            cfM[k * 4 + b] = c2;
            midA[b * 520 + 256 + k] = (hf_t)h2;
            scrB[((size_t)(b0 + b) * T_ + t) * H_ + k] = (hf_t)h2;
        }
        __syncthreads();
    }

    // ---------- Td pass: Td2[b][oc][t][e] = tanh(Ud.mid[b,t] + Udb) ----------
    {
        const h8* udf = (const h8*)(wb + W_UDF);
        for (int g = 0; g < 2; ++g) {
            const int mt = w + g * 16;                // 32 M-tiles of (b,t) rows
            const size_t arow = ((size_t)b0 * T_ + mt * 16 + fm) * H_;
            h8 A[8];
#pragma unroll
            for (int ki = 0; ki < 8; ++ki)
                A[ki] = *(const h8*)(scrB + arow + ki * 32 + fq * 8);
            for (int nt = 0; nt < 16; ++nt) {
                f4 acc = {0.f, 0.f, 0.f, 0.f};
#pragma unroll
                for (int ki = 0; ki < 8; ++ki)
                    acc = __builtin_amdgcn_mfma_f32_16x16x32_f16(A[ki], udf[(size_t)(nt * 8 + ki) * 64 + lane], acc, 0, 0, 0);
                const int o = nt * 16 + fm;
                const float bv = Udb[o];
#pragma unroll
                for (int r = 0; r < 4; ++r) {
                    int row = mt * 16 + fq * 4 + r;
                    int bb2 = row >> 7, tt = row & 127;
                    scrA[(size_t)(b0 + bb2) * 32768 + ((o >> 3) * 128 + tt) * 8 + (o & 7)]
                        = (hf_t)tanh_f(acc[r] + bv);
                }
            }
        }
    }
    __syncthreads();
    // zero decoder state: attA [h|c] rows 0-3, cfE, midA h-half rows 0-3
    for (int i = tid; i < 2048; i += TB) attA[(i >> 9) * 648 + (i & 511)] = (hf_t)0.f;
    for (int i = tid; i < 1024; i += TB) { cfE[i] = 0.f; midA[(i >> 8) * 520 + 256 + (i & 255)] = (hf_t)0.f; }
    __syncthreads();

    const float Vdb0 = Vdb[0];
    const float rb0  = rb[0];
    float* hful = cfM;   // decoder overlay [b][k] f32 (cfM unused in decoder)
    // ---------- Decoder ----------
    for (int s = 0; s < DS_; ++s) {
        // (a2) Wd GEMM -> Tah
        {
            const int nt = w;
            const h8* wv = (const h8*)(wb + W_WDF);
            f4 acc = {0.f, 0.f, 0.f, 0.f};
#pragma unroll
            for (int ki = 0; ki < 16; ++ki) {
                h8 Af = *(const h8*)(attA + fm * 648 + ki * 32 + fq * 8);
                acc = __builtin_amdgcn_mfma_f32_16x16x32_f16(Af, wv[(size_t)(nt * 16 + ki) * 64 + lane], acc, 0, 0, 0);
            }
            if (fq == 0) {
                const int k = nt * 16 + fm;
                float bv = Wdb[k];
#pragma unroll
                for (int r = 0; r < 4; ++r)
                    Tah[r * 264 + k] = (hf_t)tanh_f(acc[r] + bv);
            }
        }
        __syncthreads();
        // (b2) temporal scores (no softmax)
        {
            const int b = tid >> 8, r = tid & 255, kh = r >> 7, j = r & 127;
            const h8* up = (const h8*)(scrA + (size_t)(b0 + b) * 32768 + (size_t)kh * 16384 + (size_t)j * 8);
            float acc = 0.f;
#pragma unroll 4
            for (int i = 0; i < 16; ++i) {
                h8 u  = up[(size_t)i * 128];
                h8 ta = *(const h8*)(Tah + b * 264 + (kh * 16 + i) * 8);
                h8 ve = *(const h8*)(vdsh + (kh * 16 + i) * 8);
#pragma unroll
                for (int e = 0; e < 8; ++e) {
                    float tu = (float)u[e], taf = (float)ta[e];
                    acc = fmaf((float)ve[e] * (taf + tu),
                               __builtin_amdgcn_rcpf(fmaf(taf, tu, 1.f)), acc);
                }
            }
            spart[tid] = acc;
        }
        __syncthreads();
        if (tid < 512) {
            const int b = tid >> 7, j = tid & 127;
            sbuf[b * 128 + j] = spart[b * 256 + j] + spart[b * 256 + 128 + j] + Vdb0;
        }
        __syncthreads();
        // (c2) dec_in[b,h] = sum_j t[b,j]*mid[b,j,h] -> midA din
        {
            const int b = tid >> 8, h = tid & 255;
            const hf_t* mp = scrB + (size_t)(b0 + b) * T_ * H_ + h;
            float acc = 0.f;
#pragma unroll 8
            for (int j = 0; j < T_; ++j)
                acc = fmaf(sbuf[b * 128 + j], (float)mp[(size_t)j * H_], acc);
            midA[b * 520 + h] = (hf_t)acc;
        }
        __syncthreads();
        // (d2) dec gates
        {
            const h8* wv = (const h8*)(wb + W_DGF);
#pragma unroll
            for (int np = 0; np < 4; ++np) {
                const int nt = w * 4 + np;
                f4 acc = {0.f, 0.f, 0.f, 0.f};
#pragma unroll
                for (int ki = 0; ki < 16; ++ki) {
                    h8 Af = *(const h8*)(midA + fm * 520 + ki * 32 + fq * 8);
                    acc = __builtin_amdgcn_mfma_f32_16x16x32_f16(Af, wv[(size_t)(nt * 16 + ki) * 64 + lane], acc, 0, 0, 0);
                }
                if (fq == 0) *(f4*)(gbuf + (nt * 16 + fm) * 4) = acc;
            }
        }
        __syncthreads();
        // (e2) dec LSTM
        {
            const int b = tid >> 8, k = tid & 255;
            float gi = gbuf[k * 4 + b]           + dbih[k]       + dbhh[k];
            float gf = gbuf[(256 + k) * 4 + b]   + dbih[256 + k] + dbhh[256 + k];
            float gg = gbuf[(512 + k) * 4 + b]   + dbih[512 + k] + dbhh[512 + k];
            float go = gbuf[(768 + k) * 4 + b]   + dbih[768 + k] + dbhh[768 + k];
            float c2 = sigm(gf) * cfE[k * 4 + b] + sigm(gi) * tanh_f(gg);
            float h2 = sigm(go) * tanh_f(c2);
            cfE[k * 4 + b] = c2;
            attA[b * 648 + k]       = (hf_t)h2;
            attA[b * 648 + 256 + k] = (hf_t)c2;
            midA[b * 520 + 256 + k] = (hf_t)h2;
            hful[b * 256 + k] = h2;
        }
        __syncthreads();
        // (f2) out[b, s-6] = rW.h + rb
        if (s >= 6 && tid < 128) {
            const int b = tid >> 5, l = tid & 31;
            float p = 0.f;
#pragma unroll
            for (int i = 0; i < 8; ++i)
                p = fmaf(rW[l + i * 32], hful[b * 256 + l + i * 32], p);
            for (int d = 1; d < 32; d <<= 1) p += __shfl_xor(p, d);
            if (l == 0) out[(size_t)(b0 + b) * TD_ + (s - 6)] = p + rb0;
        }
        __syncthreads();
    }
}

extern "C" void kernel_launch(void* const* d_in, const int* in_sizes, int n_in,
                              void* d_out, int out_size, void* d_ws, size_t ws_size,
                              hipStream_t stream) {
    const float* inp  = (const float*)d_in[0];
    const float* UeW  = (const float*)d_in[2];
    const float* Ueb  = (const float*)d_in[3];
    const float* Ue2W = (const float*)d_in[4];
    const float* Ue2b = (const float*)d_in[5];
    const float* WeW  = (const float*)d_in[6];
    const float* Web  = (const float*)d_in[7];
    const float* VeW  = (const float*)d_in[8];
    const float* Veb  = (const float*)d_in[9];
    const float* UdW  = (const float*)d_in[10];
    const float* Udb  = (const float*)d_in[11];
    const float* WdW  = (const float*)d_in[12];
    const float* Wdb  = (const float*)d_in[13];
    const float* VdW  = (const float*)d_in[14];
    const float* Vdb  = (const float*)d_in[15];
    const float* eWih = (const float*)d_in[16];
    const float* eWhh = (const float*)d_in[17];
    const float* ebih = (const float*)d_in[18];
    const float* ebhh = (const float*)d_in[19];
    const float* mWih = (const float*)d_in[20];
    const float* mWhh = (const float*)d_in[21];
    const float* mbih = (const float*)d_in[22];
    const float* mbhh = (const float*)d_in[23];
    const float* dWih = (const float*)d_in[24];
    const float* dWhh = (const float*)d_in[25];
    const float* dbih = (const float*)d_in[26];
    const float* dbhh = (const float*)d_in[27];
    const float* rW   = (const float*)d_in[28];
    const float* rb   = (const float*)d_in[29];

    hf_t* wsb  = (hf_t*)d_ws;
    hf_t* scrA = wsb + SCR_A;
    hf_t* scrB = wsb + SCR_B;

    hipFuncSetAttribute((const void*)dsrnn_kernel,
                        hipFuncAttributeMaxDynamicSharedMemorySize, LDS_BYTES);

    convw_kernel<<<512, 256, 0, stream>>>(WeW, Ue2W, eWih, eWhh, mWih, mWhh,
                                          dWih, dWhh, WdW, UdW, UeW, wsb);

    dsrnn_kernel<<<B_ / BB, TB, LDS_BYTES, stream>>>(
        inp, Ueb, Ue2b, Web, VeW, Veb, Udb, Wdb, VdW, Vdb,
        ebih, ebhh, mbih, mbhh, dbih, dbhh, rW, rb,
        wsb, scrA, scrB, (float*)d_out);
}

// Round 7
// 20109.218 us; speedup vs baseline: 1.5360x; 1.0374x over previous
//
#include <hip/hip_runtime.h>

// DA-RNN persistent kernel, round 7: R6 MFMA structure +
//  (1) __launch_bounds__(1024,4) -> 128 VGPR budget (R6 got 64: serialized loads)
//  (2) nontemporal loads/stores on Tu/Td/mid streams -> weights stay L2-resident
//  (3) batched B-fragment loads (all KI loads in flight before MFMA chain)
//  (4) biases pre-staged in LDS (off the post-barrier critical path)

#define B_   1024
#define T_   128     // T_ENCO
#define NI_  128     // N_INP
#define H_   256     // N_HID
#define TD_  24      // T_DECO
#define DS_  30      // decoder steps
#define BB   4       // batch rows per workgroup
#define TB   1024    // threads per block (16 waves)

typedef _Float16 hf_t;
typedef _Float16 h8  __attribute__((ext_vector_type(8)));
typedef float    f4  __attribute__((ext_vector_type(4)));

__device__ __forceinline__ float sigm(float x) {
    return __builtin_amdgcn_rcpf(1.0f + __expf(-x));
}
__device__ __forceinline__ float tanh_f(float x) {
    float e = __expf(2.0f * x);
    return 1.0f - 2.0f * __builtin_amdgcn_rcpf(e + 1.0f);
}
__device__ __forceinline__ h8 ntl8(const hf_t* p) {
    return __builtin_nontemporal_load((const h8*)p);
}
__device__ __forceinline__ hf_t ntlh(const hf_t* p) {
    return __builtin_nontemporal_load(p);
}
__device__ __forceinline__ void ntsh(hf_t v, hf_t* p) {
    __builtin_nontemporal_store(v, p);
}

// ---- f16 weight-fragment arrays in d_ws (offsets in halves) ----
// Frag layout (R5/R6-validated):
// F[((nt*KI + ki)*64 + lane)*8 + e] = W[nt*16 + (lane&15)][ki*32 + (lane>>4)*8 + e]
#define W_WEF  0u         // [We(512)|Ue2(128)] rows 256, KI=20
#define W_EIF  163840u    // [eWih(128)|eWhh(256)] rows 1024, KI=12
#define W_MGF  557056u    // [mWih(256)|mWhh(256)] rows 1024, KI=16
#define W_DGF  1081344u   // [dWih(256)|dWhh(256)] rows 1024, KI=16
#define W_WDF  1605632u   // Wd rows 256 K=512, KI=16
#define W_UDF  1736704u   // Ud rows 256 K=256, KI=8
#define W_UEF  1802240u   // UeW rows 256 K=128, KI=4
#define SCR_A  2097152u   // Tu2 [b][kc32][j128][8] -> Td2 [b][oc32][t128][8]
#define SCR_B  35651584u  // mid [b][t][k] f16

__global__ void convw_kernel(const float* __restrict__ sWE, const float* __restrict__ sUE2,
                             const float* __restrict__ sEI, const float* __restrict__ sEH,
                             const float* __restrict__ sMI, const float* __restrict__ sMH,
                             const float* __restrict__ sDI, const float* __restrict__ sDH,
                             const float* __restrict__ sWD, const float* __restrict__ sUD,
                             const float* __restrict__ sUE,
                             hf_t* __restrict__ dst) {
    const int gtid = blockIdx.x * blockDim.x + threadIdx.x;
    const int gs   = gridDim.x * blockDim.x;
    for (int n = gtid; n < 163840; n += gs) {            // WEF KI=20
        int e = n & 7, li = (n >> 3) & 63, fi = n >> 9;
        int ki = fi % 20, nt = fi / 20;
        int row = nt * 16 + (li & 15), k = ki * 32 + (li >> 4) * 8 + e;
        float v = (k < 512) ? sWE[row * 512 + k] : sUE2[row * 128 + (k - 512)];
        dst[W_WEF + n] = (hf_t)v;
    }
    for (int n = gtid; n < 393216; n += gs) {            // EIF KI=12
        int e = n & 7, li = (n >> 3) & 63, fi = n >> 9;
        int ki = fi % 12, nt = fi / 12;
        int row = nt * 16 + (li & 15), k = ki * 32 + (li >> 4) * 8 + e;
        float v = (k < 128) ? sEI[row * 128 + k] : sEH[row * 256 + (k - 128)];
        dst[W_EIF + n] = (hf_t)v;
    }
    for (int n = gtid; n < 524288; n += gs) {            // MGF + DGF KI=16
        int e = n & 7, li = (n >> 3) & 63, fi = n >> 9;
        int ki = fi & 15, nt = fi >> 4;
        int row = nt * 16 + (li & 15), k = ki * 32 + (li >> 4) * 8 + e;
        float vm = (k < 256) ? sMI[row * 256 + k] : sMH[row * 256 + (k - 256)];
        float vd = (k < 256) ? sDI[row * 256 + k] : sDH[row * 256 + (k - 256)];
        dst[W_MGF + n] = (hf_t)vm;
        dst[W_DGF + n] = (hf_t)vd;
    }
    for (int n = gtid; n < 131072; n += gs) {            // WDF KI=16
        int e = n & 7, li = (n >> 3) & 63, fi = n >> 9;
        int ki = fi & 15, nt = fi >> 4;
        int row = nt * 16 + (li & 15), k = ki * 32 + (li >> 4) * 8 + e;
        dst[W_WDF + n] = (hf_t)sWD[row * 512 + k];
    }
    for (int n = gtid; n < 65536; n += gs) {             // UDF KI=8
        int e = n & 7, li = (n >> 3) & 63, fi = n >> 9;
        int ki = fi & 7, nt = fi >> 3;
        int row = nt * 16 + (li & 15), k = ki * 32 + (li >> 4) * 8 + e;
        dst[W_UDF + n] = (hf_t)sUD[row * 256 + k];
    }
    for (int n = gtid; n < 32768; n += gs) {             // UEF KI=4
        int e = n & 7, li = (n >> 3) & 63, fi = n >> 9;
        int ki = fi & 3, nt = fi >> 2;
        int row = nt * 16 + (li & 15), k = ki * 32 + (li >> 4) * 8 + e;
        dst[W_UEF + n] = (hf_t)sUE[row * 128 + k];
    }
}

// ---- LDS offsets (bytes) ----
#define L_ATT   0        // hf [16][648]  [h(256)|c(256)|x(128)]
#define L_ENC   20736    // hf [16][392]  [xg(128)|h(256)]
#define L_MID   33280    // hf [16][520]  [he|hm] / dec [din|h]
#define L_CFE   49920    // f32 [256][4]
#define L_CFM   54016    // f32 [256][4] ; decoder reuses as hful f32 [4][256]
#define L_VES   58112    // hf [256]
#define L_VDS   58624    // hf [256]
#define L_XH    59136    // hf [4][128]
#define L_SPART 60160    // f32 [1024]
#define L_SBUF  64256    // f32 [4][128]
#define L_TAH   66304    // hf [4][264]
#define L_BE    68416    // f32 [1024] ebih+ebhh
#define L_BM    72512    // f32 [1024] mbih+mbhh
#define L_BD    76608    // f32 [1024] dbih+dbhh
#define L_BWE   80704    // f32 [256]  Web+Ue2b
#define L_BWD   81728    // f32 [256]  Wdb
#define L_GBUF  82752    // f32 [1024][4] (16384) U XT hf [128][136] (34816)
#define LDS_BYTES 117568

__global__ __launch_bounds__(TB, 4) void dsrnn_kernel(
    const float* __restrict__ inp,
    const float* __restrict__ Ueb,
    const float* __restrict__ Ue2b,
    const float* __restrict__ Web,
    const float* __restrict__ VeW,  const float* __restrict__ Veb,
    const float* __restrict__ Udb,
    const float* __restrict__ Wdb,
    const float* __restrict__ VdW,  const float* __restrict__ Vdb,
    const float* __restrict__ ebih, const float* __restrict__ ebhh,
    const float* __restrict__ mbih, const float* __restrict__ mbhh,
    const float* __restrict__ dbih, const float* __restrict__ dbhh,
    const float* __restrict__ rW,   const float* __restrict__ rb,
    const hf_t* __restrict__ wb,
    hf_t* __restrict__ scrA, hf_t* __restrict__ scrB,
    float* __restrict__ out)
{
    extern __shared__ char smraw[];
    hf_t*  attA = (hf_t*)(smraw + L_ATT);
    hf_t*  encA = (hf_t*)(smraw + L_ENC);
    hf_t*  midA = (hf_t*)(smraw + L_MID);
    float* cfE  = (float*)(smraw + L_CFE);
    float* cfM  = (float*)(smraw + L_CFM);
    hf_t*  vesh = (hf_t*)(smraw + L_VES);
    hf_t*  vdsh = (hf_t*)(smraw + L_VDS);
    hf_t*  xh   = (hf_t*)(smraw + L_XH);
    float* spart= (float*)(smraw + L_SPART);
    float* sbuf = (float*)(smraw + L_SBUF);
    hf_t*  Tah  = (hf_t*)(smraw + L_TAH);
    float* bE   = (float*)(smraw + L_BE);
    float* bM   = (float*)(smraw + L_BM);
    float* bD   = (float*)(smraw + L_BD);
    float* bWE  = (float*)(smraw + L_BWE);
    float* bWD  = (float*)(smraw + L_BWD);
    float* gbuf = (float*)(smraw + L_GBUF);
    hf_t*  XT   = (hf_t*)(smraw + L_GBUF);

    const int tid  = threadIdx.x;
    const int b0   = blockIdx.x * BB;
    const int lane = tid & 63, w = tid >> 6;      // 16 waves
    const int fm   = lane & 15, fq = lane >> 4;

    // init: zero act buffers + c-states; stage Ve/Vd + biases
    for (int i = tid; i < 10368; i += TB) attA[i] = (hf_t)0.f;
    for (int i = tid; i < 6272;  i += TB) encA[i] = (hf_t)0.f;
    for (int i = tid; i < 8320;  i += TB) midA[i] = (hf_t)0.f;
    for (int i = tid; i < 1024;  i += TB) {
        cfE[i] = 0.f; cfM[i] = 0.f;
        bE[i] = ebih[i] + ebhh[i];
        bM[i] = mbih[i] + mbhh[i];
        bD[i] = dbih[i] + dbhh[i];
    }
    if (tid < 256) {
        vesh[tid] = (hf_t)VeW[tid]; vdsh[tid] = (hf_t)VdW[tid];
        bWE[tid] = Web[tid] + Ue2b[tid]; bWD[tid] = Wdb[tid];
    }

    // ---------- Phase 0: Tu2[b][kc][j][e] = tanh(sum_t X[t,j]*UeW[k,t]+Ueb[k]) ----------
    {
        const h8* uef = (const h8*)(wb + W_UEF);
        for (int b = 0; b < BB; ++b) {
            __syncthreads();
            for (int i = tid; i < 16384; i += TB) {
                int t0 = i >> 7, j = i & 127;
                XT[j * 136 + t0] = (hf_t)inp[((size_t)(b0 + b) * T_ + t0) * NI_ + j];
            }
            __syncthreads();
            const int mt = w & 7, ng = w >> 3;
            h8 A[4];
#pragma unroll
            for (int ki = 0; ki < 4; ++ki)
                A[ki] = *(const h8*)(XT + (mt * 16 + fm) * 136 + ki * 32 + fq * 8);
            hf_t* tub = scrA + (size_t)(b0 + b) * 32768;
            for (int p = 0; p < 8; ++p) {
                const int nt = ng * 8 + p;
                h8 Bf[4];
#pragma unroll
                for (int ki = 0; ki < 4; ++ki)
                    Bf[ki] = uef[(size_t)(nt * 4 + ki) * 64 + lane];
                f4 acc = {0.f, 0.f, 0.f, 0.f};
#pragma unroll
                for (int ki = 0; ki < 4; ++ki)
                    acc = __builtin_amdgcn_mfma_f32_16x16x32_f16(A[ki], Bf[ki], acc, 0, 0, 0);
                const int o = nt * 16 + fm;
                const float bv = Ueb[o];
#pragma unroll
                for (int r = 0; r < 4; ++r) {
                    int j = mt * 16 + fq * 4 + r;
                    ntsh((hf_t)tanh_f(acc[r] + bv), tub + ((o >> 3) * 128 + j) * 8 + (o & 7));
                }
            }
        }
    }
    __syncthreads();

    // ---------- Fused encoder + mid loop ----------
    for (int t = 0; t < T_; ++t) {
        // (a) stage x_t
        if (tid < 512) {
            int b = tid >> 7, j = tid & 127;
            float v = inp[((size_t)(b0 + b) * T_ + t) * NI_ + j];
            xh[b * 128 + j] = (hf_t)v;
            attA[b * 648 + 512 + j] = (hf_t)v;
        }
        __syncthreads();
        // (b) att GEMM: Tah = tanh(We.[h;c] + Ue2.x + biases)
        {
            const int nt = w;
            const h8* wv = (const h8*)(wb + W_WEF);
            h8 Bf[20];
#pragma unroll
            for (int ki = 0; ki < 20; ++ki)
                Bf[ki] = wv[(size_t)(nt * 20 + ki) * 64 + lane];
            f4 acc = {0.f, 0.f, 0.f, 0.f};
#pragma unroll
            for (int ki = 0; ki < 20; ++ki) {
                h8 Af = *(const h8*)(attA + fm * 648 + ki * 32 + fq * 8);
                acc = __builtin_amdgcn_mfma_f32_16x16x32_f16(Af, Bf[ki], acc, 0, 0, 0);
            }
            if (fq == 0) {
                const int k = nt * 16 + fm;
                float bv = bWE[k];
#pragma unroll
                for (int r = 0; r < 4; ++r)
                    Tah[r * 264 + k] = (hf_t)tanh_f(acc[r] + bv);
            }
        }
        __syncthreads();
        // (c) scores via tanh identity (k-half split), nt stream loads
        {
            const int b = tid >> 8, r = tid & 255, kh = r >> 7, j = r & 127;
            const hf_t* up = scrA + (size_t)(b0 + b) * 32768 + (size_t)kh * 16384 + (size_t)j * 8;
            float acc = 0.f;
#pragma unroll 4
            for (int i = 0; i < 16; ++i) {
                h8 u  = ntl8(up + (size_t)i * 1024);
                h8 ta = *(const h8*)(Tah + b * 264 + (kh * 16 + i) * 8);
                h8 ve = *(const h8*)(vesh + (kh * 16 + i) * 8);
#pragma unroll
                for (int e = 0; e < 8; ++e) {
                    float tu = (float)u[e], taf = (float)ta[e];
                    acc = fmaf((float)ve[e] * (taf + tu),
                               __builtin_amdgcn_rcpf(fmaf(taf, tu, 1.f)), acc);
                }
            }
            spart[tid] = acc;
        }
        __syncthreads();
        // (d) softmax per b (wave w<4 <-> b=w), gate x -> encA xg
        if (w < 4) {
            const int b = w;
            float s0 = spart[b * 256 + lane]      + spart[b * 256 + 128 + lane];
            float s1 = spart[b * 256 + 64 + lane] + spart[b * 256 + 192 + lane];
            float mx = fmaxf(s0, s1);
            for (int d = 1; d < 64; d <<= 1) mx = fmaxf(mx, __shfl_xor(mx, d));
            float e0 = __expf(s0 - mx), e1 = __expf(s1 - mx);
            float ss = e0 + e1;
            for (int d = 1; d < 64; d <<= 1) ss += __shfl_xor(ss, d);
            float inv = 1.f / ss;
            encA[b * 392 + lane]      = (hf_t)((float)xh[b * 128 + lane] * e0 * inv);
            encA[b * 392 + 64 + lane] = (hf_t)((float)xh[b * 128 + 64 + lane] * e1 * inv);
        }
        __syncthreads();
        // (e) enc gates -> gbuf[o][4]
        {
            const h8* wv = (const h8*)(wb + W_EIF);
            h8 Ae[12];
#pragma unroll
            for (int ki = 0; ki < 12; ++ki)
                Ae[ki] = *(const h8*)(encA + fm * 392 + ki * 32 + fq * 8);
#pragma unroll
            for (int np = 0; np < 4; ++np) {
                const int nt = w * 4 + np;
                h8 Bf[12];
#pragma unroll
                for (int ki = 0; ki < 12; ++ki)
                    Bf[ki] = wv[(size_t)(nt * 12 + ki) * 64 + lane];
                f4 acc = {0.f, 0.f, 0.f, 0.f};
#pragma unroll
                for (int ki = 0; ki < 12; ++ki)
                    acc = __builtin_amdgcn_mfma_f32_16x16x32_f16(Ae[ki], Bf[ki], acc, 0, 0, 0);
                if (fq == 0) *(f4*)(gbuf + (nt * 16 + fm) * 4) = acc;
            }
        }
        __syncthreads();
        // (f) enc LSTM
        {
            const int b = tid >> 8, k = tid & 255;
            float gi = gbuf[k * 4 + b]           + bE[k];
            float gf = gbuf[(256 + k) * 4 + b]   + bE[256 + k];
            float gg = gbuf[(512 + k) * 4 + b]   + bE[512 + k];
            float go = gbuf[(768 + k) * 4 + b]   + bE[768 + k];
            float c2 = sigm(gf) * cfE[k * 4 + b] + sigm(gi) * tanh_f(gg);
            float h2 = sigm(go) * tanh_f(c2);
            cfE[k * 4 + b] = c2;
            attA[b * 648 + k]       = (hf_t)h2;
            attA[b * 648 + 256 + k] = (hf_t)c2;
            encA[b * 392 + 128 + k] = (hf_t)h2;
            midA[b * 520 + k]       = (hf_t)h2;
        }
        __syncthreads();
        // (g) mid gates
        {
            const h8* wv = (const h8*)(wb + W_MGF);
#pragma unroll
            for (int np = 0; np < 4; ++np) {
                const int nt = w * 4 + np;
                h8 Bf[16];
#pragma unroll
                for (int ki = 0; ki < 16; ++ki)
                    Bf[ki] = wv[(size_t)(nt * 16 + ki) * 64 + lane];
                f4 acc = {0.f, 0.f, 0.f, 0.f};
#pragma unroll
                for (int ki = 0; ki < 16; ++ki) {
                    h8 Af = *(const h8*)(midA + fm * 520 + ki * 32 + fq * 8);
                    acc = __builtin_amdgcn_mfma_f32_16x16x32_f16(Af, Bf[ki], acc, 0, 0, 0);
                }
                if (fq == 0) *(f4*)(gbuf + (nt * 16 + fm) * 4) = acc;
            }
        }
        __syncthreads();
        // (h) mid LSTM + store mid (nt)
        {
            const int b = tid >> 8, k = tid & 255;
            float gi = gbuf[k * 4 + b]           + bM[k];
            float gf = gbuf[(256 + k) * 4 + b]   + bM[256 + k];
            float gg = gbuf[(512 + k) * 4 + b]   + bM[512 + k];
            float go = gbuf[(768 + k) * 4 + b]   + bM[768 + k];
            float c2 = sigm(gf) * cfM[k * 4 + b] + sigm(gi) * tanh_f(gg);
            float h2 = sigm(go) * tanh_f(c2);
            cfM[k * 4 + b] = c2;
            midA[b * 520 + 256 + k] = (hf_t)h2;
            ntsh((hf_t)h2, scrB + ((size_t)(b0 + b) * T_ + t) * H_ + k);
        }
        __syncthreads();
    }

    // ---------- Td pass: Td2[b][oc][t][e] = tanh(Ud.mid[b,t] + Udb) ----------
    {
        const h8* udf = (const h8*)(wb + W_UDF);
        for (int g = 0; g < 2; ++g) {
            const int mt = w + g * 16;                // 32 M-tiles of (b,t) rows
            const size_t arow = ((size_t)b0 * T_ + mt * 16 + fm) * H_;
            h8 A[8];
#pragma unroll
            for (int ki = 0; ki < 8; ++ki)
                A[ki] = ntl8(scrB + arow + ki * 32 + fq * 8);
            for (int nt = 0; nt < 16; ++nt) {
                h8 Bf[8];
#pragma unroll
                for (int ki = 0; ki < 8; ++ki)
                    Bf[ki] = udf[(size_t)(nt * 8 + ki) * 64 + lane];
                f4 acc = {0.f, 0.f, 0.f, 0.f};
#pragma unroll
                for (int ki = 0; ki < 8; ++ki)
                    acc = __builtin_amdgcn_mfma_f32_16x16x32_f16(A[ki], Bf[ki], acc, 0, 0, 0);
                const int o = nt * 16 + fm;
                const float bv = Udb[o];
#pragma unroll
                for (int r = 0; r < 4; ++r) {
                    int row = mt * 16 + fq * 4 + r;
                    int bb2 = row >> 7, tt = row & 127;
                    ntsh((hf_t)tanh_f(acc[r] + bv),
                         scrA + (size_t)(b0 + bb2) * 32768 + ((o >> 3) * 128 + tt) * 8 + (o & 7));
                }
            }
        }
    }
    __syncthreads();
    // zero decoder state: attA [h|c] rows 0-3, cfE, midA h-half rows 0-3
    for (int i = tid; i < 2048; i += TB) attA[(i >> 9) * 648 + (i & 511)] = (hf_t)0.f;
    for (int i = tid; i < 1024; i += TB) { cfE[i] = 0.f; midA[(i >> 8) * 520 + 256 + (i & 255)] = (hf_t)0.f; }
    __syncthreads();

    const float Vdb0 = Vdb[0];
    const float rb0  = rb[0];
    float* hful = cfM;   // decoder overlay [b][k] f32
    // ---------- Decoder ----------
    for (int s = 0; s < DS_; ++s) {
        // (a2) Wd GEMM -> Tah
        {
            const int nt = w;
            const h8* wv = (const h8*)(wb + W_WDF);
            h8 Bf[16];
#pragma unroll
            for (int ki = 0; ki < 16; ++ki)
                Bf[ki] = wv[(size_t)(nt * 16 + ki) * 64 + lane];
            f4 acc = {0.f, 0.f, 0.f, 0.f};
#pragma unroll
            for (int ki = 0; ki < 16; ++ki) {
                h8 Af = *(const h8*)(attA + fm * 648 + ki * 32 + fq * 8);
                acc = __builtin_amdgcn_mfma_f32_16x16x32_f16(Af, Bf[ki], acc, 0, 0, 0);
            }
            if (fq == 0) {
                const int k = nt * 16 + fm;
                float bv = bWD[k];
#pragma unroll
                for (int r = 0; r < 4; ++r)
                    Tah[r * 264 + k] = (hf_t)tanh_f(acc[r] + bv);
            }
        }
        __syncthreads();
        // (b2) temporal scores (no softmax), nt loads
        {
            const int b = tid >> 8, r = tid & 255, kh = r >> 7, j = r & 127;
            const hf_t* up = scrA + (size_t)(b0 + b) * 32768 + (size_t)kh * 16384 + (size_t)j * 8;
            float acc = 0.f;
#pragma unroll 4
            for (int i = 0; i < 16; ++i) {
                h8 u  = ntl8(up + (size_t)i * 1024);
                h8 ta = *(const h8*)(Tah + b * 264 + (kh * 16 + i) * 8);
                h8 ve = *(const h8*)(vdsh + (kh * 16 + i) * 8);
#pragma unroll
                for (int e = 0; e < 8; ++e) {
                    float tu = (float)u[e], taf = (float)ta[e];
                    acc = fmaf((float)ve[e] * (taf + tu),
                               __builtin_amdgcn_rcpf(fmaf(taf, tu, 1.f)), acc);
                }
            }
            spart[tid] = acc;
        }
        __syncthreads();
        if (tid < 512) {
            const int b = tid >> 7, j = tid & 127;
            sbuf[b * 128 + j] = spart[b * 256 + j] + spart[b * 256 + 128 + j] + Vdb0;
        }
        __syncthreads();
        // (c2) dec_in[b,h] = sum_j t[b,j]*mid[b,j,h] -> midA din (nt loads)
        {
            const int b = tid >> 8, h = tid & 255;
            const hf_t* mp = scrB + (size_t)(b0 + b) * T_ * H_ + h;
            float acc = 0.f;
#pragma unroll 8
            for (int j = 0; j < T_; ++j)
                acc = fmaf(sbuf[b * 128 + j], (float)ntlh(mp + (size_t)j * H_), acc);
            midA[b * 520 + h] = (hf_t)acc;
        }
        __syncthreads();
        // (d2) dec gates
        {
            const h8* wv = (const h8*)(wb + W_DGF);
#pragma unroll
            for (int np = 0; np < 4; ++np) {
                const int nt = w * 4 + np;
                h8 Bf[16];
#pragma unroll
                for (int ki = 0; ki < 16; ++ki)
                    Bf[ki] = wv[(size_t)(nt * 16 + ki) * 64 + lane];
                f4 acc = {0.f, 0.f, 0.f, 0.f};
#pragma unroll
                for (int ki = 0; ki < 16; ++ki) {
                    h8 Af = *(const h8*)(midA + fm * 520 + ki * 32 + fq * 8);
                    acc = __builtin_amdgcn_mfma_f32_16x16x32_f16(Af, Bf[ki], acc, 0, 0, 0);
                }
                if (fq == 0) *(f4*)(gbuf + (nt * 16 + fm) * 4) = acc;
            }
        }
        __syncthreads();
        // (e2) dec LSTM
        {
            const int b = tid >> 8, k = tid & 255;
            float gi = gbuf[k * 4 + b]           + bD[k];
            float gf = gbuf[(256 + k) * 4 + b]   + bD[256 + k];
            float gg = gbuf[(512 + k) * 4 + b]   + bD[512 + k];
            float go = gbuf[(768 + k) * 4 + b]   + bD[768 + k];
            float c2 = sigm(gf) * cfE[k * 4 + b] + sigm(gi) * tanh_f(gg);
            float h2 = sigm(go) * tanh_f(c2);
            cfE[k * 4 + b] = c2;
            attA[b * 648 + k]       = (hf_t)h2;
            attA[b * 648 + 256 + k] = (hf_t)c2;
            midA[b * 520 + 256 + k] = (hf_t)h2;
            hful[b * 256 + k] = h2;
        }
        __syncthreads();
        // (f2) out[b, s-6] = rW.h + rb
        if (s >= 6 && tid < 128) {
            const int b = tid >> 5, l = tid & 31;
            float p = 0.f;
#pragma unroll
            for (int i = 0; i < 8; ++i)
                p = fmaf(rW[l + i * 32], hful[b * 256 + l + i * 32], p);
            for (int d = 1; d < 32; d <<= 1) p += __shfl_xor(p, d);
            if (l == 0) out[(size_t)(b0 + b) * TD_ + (s - 6)] = p + rb0;
        }
        __syncthreads();
    }
}

extern "C" void kernel_launch(void* const* d_in, const int* in_sizes, int n_in,
                              void* d_out, int out_size, void* d_ws, size_t ws_size,
                              hipStream_t stream) {
    const float* inp  = (const float*)d_in[0];
    const float* UeW  = (const float*)d_in[2];
    const float* Ueb  = (const float*)d_in[3];
    const float* Ue2W = (const float*)d_in[4];
    const float* Ue2b = (const float*)d_in[5];
    const float* WeW  = (const float*)d_in[6];
    const float* Web  = (const float*)d_in[7];
    const float* VeW  = (const float*)d_in[8];
    const float* Veb  = (const float*)d_in[9];
    const float* UdW  = (const float*)d_in[10];
    const float* Udb  = (const float*)d_in[11];
    const float* WdW  = (const float*)d_in[12];
    const float* Wdb  = (const float*)d_in[13];
    const float* VdW  = (const float*)d_in[14];
    const float* Vdb  = (const float*)d_in[15];
    const float* eWih = (const float*)d_in[16];
    const float* eWhh = (const float*)d_in[17];
    const float* ebih = (const float*)d_in[18];
    const float* ebhh = (const float*)d_in[19];
    const float* mWih = (const float*)d_in[20];
    const float* mWhh = (const float*)d_in[21];
    const float* mbih = (const float*)d_in[22];
    const float* mbhh = (const float*)d_in[23];
    const float* dWih = (const float*)d_in[24];
    const float* dWhh = (const float*)d_in[25];
    const float* dbih = (const float*)d_in[26];
    const float* dbhh = (const float*)d_in[27];
    const float* rW   = (const float*)d_in[28];
    const float* rb   = (const float*)d_in[29];

    hf_t* wsb  = (hf_t*)d_ws;
    hf_t* scrA = wsb + SCR_A;
    hf_t* scrB = wsb + SCR_B;

    hipFuncSetAttribute((const void*)dsrnn_kernel,
                        hipFuncAttributeMaxDynamicSharedMemorySize, LDS_BYTES);

    convw_kernel<<<512, 256, 0, stream>>>(WeW, Ue2W, eWih, eWhh, mWih, mWhh,
                                          dWih, dWhh, WdW, UdW, UeW, wsb);

    dsrnn_kernel<<<B_ / BB, TB, LDS_BYTES, stream>>>(
        inp, Ueb, Ue2b, Web, VeW, Veb, Udb, Wdb, VdW, Vdb,
        ebih, ebhh, mbih, mbhh, dbih, dbhh, rW, rb,
        wsb, scrA, scrB, (float*)d_out);
}

// Round 8
// 17617.775 us; speedup vs baseline: 1.7532x; 1.1414x over previous
//
#include <hip/hip_runtime.h>

// DA-RNN persistent kernel, round 8: R7 MFMA structure +
//  (1) scrA/scrB stream traffic via sc0 sc1 nt (system scope = L2 bypass):
//      stores write-through, loads batched 8/asm-block -> weights stay L2-resident
//  (2) amdgpu_waves_per_eu(4,4) -> real 128-VGPR budget (R7 compiled at 64)
//  (3) dec_in einsum: j-split batched dword loads + LDS combine

#define B_   1024
#define T_   128     // T_ENCO
#define NI_  128     // N_INP
#define H_   256     // N_HID
#define TD_  24      // T_DECO
#define DS_  30      // decoder steps
#define BB   4       // batch rows per workgroup
#define TB   1024    // threads per block (16 waves)

typedef _Float16 hf_t;
typedef _Float16 h8  __attribute__((ext_vector_type(8)));
typedef float    f4  __attribute__((ext_vector_type(4)));

__device__ __forceinline__ float sigm(float x) {
    return __builtin_amdgcn_rcpf(1.0f + __expf(-x));
}
__device__ __forceinline__ float tanh_f(float x) {
    float e = __expf(2.0f * x);
    return 1.0f - 2.0f * __builtin_amdgcn_rcpf(e + 1.0f);
}

// ---- system-scope (L2-bypass) stream access helpers ----
__device__ __forceinline__ void vm_drain() {
    asm volatile("s_waitcnt vmcnt(0)" ::: "memory");
}
__device__ __forceinline__ void scs_u16(hf_t v, hf_t* p) {
    asm volatile("global_store_short %0, %1, off sc0 sc1 nt"
                 :: "v"(p), "v"(v) : "memory");
}
// 8 x 16B loads at p + i*strideBytes, L2-bypassed, all in flight then drained
__device__ __forceinline__ void scl8(const hf_t* p, int strideBytes, h8* o) {
    const char* c = (const char*)p;
    asm volatile(
        "global_load_dwordx4 %0, %8, off sc0 sc1 nt\n\t"
        "global_load_dwordx4 %1, %9, off sc0 sc1 nt\n\t"
        "global_load_dwordx4 %2, %10, off sc0 sc1 nt\n\t"
        "global_load_dwordx4 %3, %11, off sc0 sc1 nt\n\t"
        "global_load_dwordx4 %4, %12, off sc0 sc1 nt\n\t"
        "global_load_dwordx4 %5, %13, off sc0 sc1 nt\n\t"
        "global_load_dwordx4 %6, %14, off sc0 sc1 nt\n\t"
        "global_load_dwordx4 %7, %15, off sc0 sc1 nt\n\t"
        "s_waitcnt vmcnt(0)"
        : "=&v"(o[0]), "=&v"(o[1]), "=&v"(o[2]), "=&v"(o[3]),
          "=&v"(o[4]), "=&v"(o[5]), "=&v"(o[6]), "=&v"(o[7])
        : "v"(c), "v"(c + strideBytes), "v"(c + 2 * strideBytes), "v"(c + 3 * strideBytes),
          "v"(c + 4 * strideBytes), "v"(c + 5 * strideBytes), "v"(c + 6 * strideBytes),
          "v"(c + 7 * strideBytes)
        : "memory");
}
// 8 x 4B loads at p + i*strideBytes
__device__ __forceinline__ void scl8d(const char* c, int strideBytes, unsigned int* o) {
    asm volatile(
        "global_load_dword %0, %8, off sc0 sc1 nt\n\t"
        "global_load_dword %1, %9, off sc0 sc1 nt\n\t"
        "global_load_dword %2, %10, off sc0 sc1 nt\n\t"
        "global_load_dword %3, %11, off sc0 sc1 nt\n\t"
        "global_load_dword %4, %12, off sc0 sc1 nt\n\t"
        "global_load_dword %5, %13, off sc0 sc1 nt\n\t"
        "global_load_dword %6, %14, off sc0 sc1 nt\n\t"
        "global_load_dword %7, %15, off sc0 sc1 nt\n\t"
        "s_waitcnt vmcnt(0)"
        : "=&v"(o[0]), "=&v"(o[1]), "=&v"(o[2]), "=&v"(o[3]),
          "=&v"(o[4]), "=&v"(o[5]), "=&v"(o[6]), "=&v"(o[7])
        : "v"(c), "v"(c + strideBytes), "v"(c + 2 * strideBytes), "v"(c + 3 * strideBytes),
          "v"(c + 4 * strideBytes), "v"(c + 5 * strideBytes), "v"(c + 6 * strideBytes),
          "v"(c + 7 * strideBytes)
        : "memory");
}

// ---- f16 weight-fragment arrays in d_ws (offsets in halves) ----
// F[((nt*KI + ki)*64 + lane)*8 + e] = W[nt*16 + (lane&15)][ki*32 + (lane>>4)*8 + e]
#define W_WEF  0u         // [We(512)|Ue2(128)] rows 256, KI=20
#define W_EIF  163840u    // [eWih(128)|eWhh(256)] rows 1024, KI=12
#define W_MGF  557056u    // [mWih(256)|mWhh(256)] rows 1024, KI=16
#define W_DGF  1081344u   // [dWih(256)|dWhh(256)] rows 1024, KI=16
#define W_WDF  1605632u   // Wd rows 256 K=512, KI=16
#define W_UDF  1736704u   // Ud rows 256 K=256, KI=8
#define W_UEF  1802240u   // UeW rows 256 K=128, KI=4
#define SCR_A  2097152u   // Tu2 [b][kc32][j128][8] -> Td2 [b][oc32][t128][8]
#define SCR_B  35651584u  // mid [b][t][k] f16

__global__ void convw_kernel(const float* __restrict__ sWE, const float* __restrict__ sUE2,
                             const float* __restrict__ sEI, const float* __restrict__ sEH,
                             const float* __restrict__ sMI, const float* __restrict__ sMH,
                             const float* __restrict__ sDI, const float* __restrict__ sDH,
                             const float* __restrict__ sWD, const float* __restrict__ sUD,
                             const float* __restrict__ sUE,
                             hf_t* __restrict__ dst) {
    const int gtid = blockIdx.x * blockDim.x + threadIdx.x;
    const int gs   = gridDim.x * blockDim.x;
    for (int n = gtid; n < 163840; n += gs) {            // WEF KI=20
        int e = n & 7, li = (n >> 3) & 63, fi = n >> 9;
        int ki = fi % 20, nt = fi / 20;
        int row = nt * 16 + (li & 15), k = ki * 32 + (li >> 4) * 8 + e;
        float v = (k < 512) ? sWE[row * 512 + k] : sUE2[row * 128 + (k - 512)];
        dst[W_WEF + n] = (hf_t)v;
    }
    for (int n = gtid; n < 393216; n += gs) {            // EIF KI=12
        int e = n & 7, li = (n >> 3) & 63, fi = n >> 9;
        int ki = fi % 12, nt = fi / 12;
        int row = nt * 16 + (li & 15), k = ki * 32 + (li >> 4) * 8 + e;
        float v = (k < 128) ? sEI[row * 128 + k] : sEH[row * 256 + (k - 128)];
        dst[W_EIF + n] = (hf_t)v;
    }
    for (int n = gtid; n < 524288; n += gs) {            // MGF + DGF KI=16
        int e = n & 7, li = (n >> 3) & 63, fi = n >> 9;
        int ki = fi & 15, nt = fi >> 4;
        int row = nt * 16 + (li & 15), k = ki * 32 + (li >> 4) * 8 + e;
        float vm = (k < 256) ? sMI[row * 256 + k] : sMH[row * 256 + (k - 256)];
        float vd = (k < 256) ? sDI[row * 256 + k] : sDH[row * 256 + (k - 256)];
        dst[W_MGF + n] = (hf_t)vm;
        dst[W_DGF + n] = (hf_t)vd;
    }
    for (int n = gtid; n < 131072; n += gs) {            // WDF KI=16
        int e = n & 7, li = (n >> 3) & 63, fi = n >> 9;
        int ki = fi & 15, nt = fi >> 4;
        int row = nt * 16 + (li & 15), k = ki * 32 + (li >> 4) * 8 + e;
        dst[W_WDF + n] = (hf_t)sWD[row * 512 + k];
    }
    for (int n = gtid; n < 65536; n += gs) {             // UDF KI=8
        int e = n & 7, li = (n >> 3) & 63, fi = n >> 9;
        int ki = fi & 7, nt = fi >> 3;
        int row = nt * 16 + (li & 15), k = ki * 32 + (li >> 4) * 8 + e;
        dst[W_UDF + n] = (hf_t)sUD[row * 256 + k];
    }
    for (int n = gtid; n < 32768; n += gs) {             // UEF KI=4
        int e = n & 7, li = (n >> 3) & 63, fi = n >> 9;
        int ki = fi & 3, nt = fi >> 2;
        int row = nt * 16 + (li & 15), k = ki * 32 + (li >> 4) * 8 + e;
        dst[W_UEF + n] = (hf_t)sUE[row * 128 + k];
    }
}

// ---- LDS offsets (bytes) ----
#define L_ATT   0        // hf [16][648]  [h(256)|c(256)|x(128)]
#define L_ENC   20736    // hf [16][392]  [xg(128)|h(256)]
#define L_MID   33280    // hf [16][520]  [he|hm] / dec [din|h]
#define L_CFE   49920    // f32 [256][4]
#define L_CFM   54016    // f32 [256][4] ; decoder reuses as hful f32 [4][256]
#define L_VES   58112    // hf [256]
#define L_VDS   58624    // hf [256]
#define L_XH    59136    // hf [4][128]
#define L_SPART 60160    // f32 [1024]
#define L_SBUF  64256    // f32 [4][128]
#define L_TAH   66304    // hf [4][264]
#define L_BE    68416    // f32 [1024] ebih+ebhh
#define L_BM    72512    // f32 [1024] mbih+mbhh
#define L_BD    76608    // f32 [1024] dbih+dbhh
#define L_BWE   80704    // f32 [256]  Web+Ue2b
#define L_BWD   81728    // f32 [256]  Wdb
#define L_GBUF  82752    // f32 [1024][4] (16384) U XT hf [128][136] (34816) U dec partials [1024][2]
#define LDS_BYTES 117568

__global__ __attribute__((amdgpu_flat_work_group_size(TB, TB), amdgpu_waves_per_eu(4, 4)))
void dsrnn_kernel(
    const float* __restrict__ inp,
    const float* __restrict__ Ueb,
    const float* __restrict__ Ue2b,
    const float* __restrict__ Web,
    const float* __restrict__ VeW,  const float* __restrict__ Veb,
    const float* __restrict__ Udb,
    const float* __restrict__ Wdb,
    const float* __restrict__ VdW,  const float* __restrict__ Vdb,
    const float* __restrict__ ebih, const float* __restrict__ ebhh,
    const float* __restrict__ mbih, const float* __restrict__ mbhh,
    const float* __restrict__ dbih, const float* __restrict__ dbhh,
    const float* __restrict__ rW,   const float* __restrict__ rb,
    const hf_t* __restrict__ wb,
    hf_t* __restrict__ scrA, hf_t* __restrict__ scrB,
    float* __restrict__ out)
{
    extern __shared__ char smraw[];
    hf_t*  attA = (hf_t*)(smraw + L_ATT);
    hf_t*  encA = (hf_t*)(smraw + L_ENC);
    hf_t*  midA = (hf_t*)(smraw + L_MID);
    float* cfE  = (float*)(smraw + L_CFE);
    float* cfM  = (float*)(smraw + L_CFM);
    hf_t*  vesh = (hf_t*)(smraw + L_VES);
    hf_t*  vdsh = (hf_t*)(smraw + L_VDS);
    hf_t*  xh   = (hf_t*)(smraw + L_XH);
    float* spart= (float*)(smraw + L_SPART);
    float* sbuf = (float*)(smraw + L_SBUF);
    hf_t*  Tah  = (hf_t*)(smraw + L_TAH);
    float* bE   = (float*)(smraw + L_BE);
    float* bM   = (float*)(smraw + L_BM);
    float* bD   = (float*)(smraw + L_BD);
    float* bWE  = (float*)(smraw + L_BWE);
    float* bWD  = (float*)(smraw + L_BWD);
    float* gbuf = (float*)(smraw + L_GBUF);
    hf_t*  XT   = (hf_t*)(smraw + L_GBUF);

    const int tid  = threadIdx.x;
    const int b0   = blockIdx.x * BB;
    const int lane = tid & 63, w = tid >> 6;      // 16 waves
    const int fm   = lane & 15, fq = lane >> 4;

    // init: zero act buffers + c-states; stage Ve/Vd + biases
    for (int i = tid; i < 10368; i += TB) attA[i] = (hf_t)0.f;
    for (int i = tid; i < 6272;  i += TB) encA[i] = (hf_t)0.f;
    for (int i = tid; i < 8320;  i += TB) midA[i] = (hf_t)0.f;
    for (int i = tid; i < 1024;  i += TB) {
        cfE[i] = 0.f; cfM[i] = 0.f;
        bE[i] = ebih[i] + ebhh[i];
        bM[i] = mbih[i] + mbhh[i];
        bD[i] = dbih[i] + dbhh[i];
    }
    if (tid < 256) {
        vesh[tid] = (hf_t)VeW[tid]; vdsh[tid] = (hf_t)VdW[tid];
        bWE[tid] = Web[tid] + Ue2b[tid]; bWD[tid] = Wdb[tid];
    }

    // ---------- Phase 0: Tu2[b][kc][j][e] = tanh(sum_t X[t,j]*UeW[k,t]+Ueb[k]) ----------
    {
        const h8* uef = (const h8*)(wb + W_UEF);
        for (int b = 0; b < BB; ++b) {
            __syncthreads();
            for (int i = tid; i < 16384; i += TB) {
                int t0 = i >> 7, j = i & 127;
                XT[j * 136 + t0] = (hf_t)inp[((size_t)(b0 + b) * T_ + t0) * NI_ + j];
            }
            __syncthreads();
            const int mt = w & 7, ng = w >> 3;
            h8 A[4];
#pragma unroll
            for (int ki = 0; ki < 4; ++ki)
                A[ki] = *(const h8*)(XT + (mt * 16 + fm) * 136 + ki * 32 + fq * 8);
            hf_t* tub = scrA + (size_t)(b0 + b) * 32768;
            for (int p = 0; p < 8; ++p) {
                const int nt = ng * 8 + p;
                h8 Bf[4];
#pragma unroll
                for (int ki = 0; ki < 4; ++ki)
                    Bf[ki] = uef[(size_t)(nt * 4 + ki) * 64 + lane];
                f4 acc = {0.f, 0.f, 0.f, 0.f};
#pragma unroll
                for (int ki = 0; ki < 4; ++ki)
                    acc = __builtin_amdgcn_mfma_f32_16x16x32_f16(A[ki], Bf[ki], acc, 0, 0, 0);
                const int o = nt * 16 + fm;
                const float bv = Ueb[o];
#pragma unroll
                for (int r = 0; r < 4; ++r) {
                    int j = mt * 16 + fq * 4 + r;
                    scs_u16((hf_t)tanh_f(acc[r] + bv), tub + ((o >> 3) * 128 + j) * 8 + (o & 7));
                }
            }
        }
    }
    vm_drain();
    __syncthreads();

    // ---------- Fused encoder + mid loop ----------
    for (int t = 0; t < T_; ++t) {
        // (a) stage x_t
        if (tid < 512) {
            int b = tid >> 7, j = tid & 127;
            float v = inp[((size_t)(b0 + b) * T_ + t) * NI_ + j];
            xh[b * 128 + j] = (hf_t)v;
            attA[b * 648 + 512 + j] = (hf_t)v;
        }
        __syncthreads();
        // (b) att GEMM: Tah = tanh(We.[h;c] + Ue2.x + biases)
        {
            const int nt = w;
            const h8* wv = (const h8*)(wb + W_WEF);
            h8 Bf[20];
#pragma unroll
            for (int ki = 0; ki < 20; ++ki)
                Bf[ki] = wv[(size_t)(nt * 20 + ki) * 64 + lane];
            f4 acc = {0.f, 0.f, 0.f, 0.f};
#pragma unroll
            for (int ki = 0; ki < 20; ++ki) {
                h8 Af = *(const h8*)(attA + fm * 648 + ki * 32 + fq * 8);
                acc = __builtin_amdgcn_mfma_f32_16x16x32_f16(Af, Bf[ki], acc, 0, 0, 0);
            }
            if (fq == 0) {
                const int k = nt * 16 + fm;
                float bv = bWE[k];
#pragma unroll
                for (int r = 0; r < 4; ++r)
                    Tah[r * 264 + k] = (hf_t)tanh_f(acc[r] + bv);
            }
        }
        __syncthreads();
        // (c) scores via tanh identity, L2-bypass batched loads
        {
            const int b = tid >> 8, r = tid & 255, kh = r >> 7, j = r & 127;
            const hf_t* up = scrA + (size_t)(b0 + b) * 32768 + (size_t)kh * 16384 + (size_t)j * 8;
            float acc = 0.f;
#pragma unroll
            for (int g = 0; g < 2; ++g) {
                h8 u[8];
                scl8(up + (size_t)g * 8192, 2048, u);
#pragma unroll
                for (int i = 0; i < 8; ++i) {
                    const int kc = kh * 16 + g * 8 + i;
                    h8 ta = *(const h8*)(Tah + b * 264 + kc * 8);
                    h8 ve = *(const h8*)(vesh + kc * 8);
#pragma unroll
                    for (int e = 0; e < 8; ++e) {
                        float tu = (float)u[i][e], taf = (float)ta[e];
                        acc = fmaf((float)ve[e] * (taf + tu),
                                   __builtin_amdgcn_rcpf(fmaf(taf, tu, 1.f)), acc);
                    }
                }
            }
            spart[tid] = acc;
        }
        __syncthreads();
        // (d) softmax per b (wave w<4 <-> b=w), gate x -> encA xg
        if (w < 4) {
            const int b = w;
            float s0 = spart[b * 256 + lane]      + spart[b * 256 + 128 + lane];
            float s1 = spart[b * 256 + 64 + lane] + spart[b * 256 + 192 + lane];
            float mx = fmaxf(s0, s1);
            for (int d = 1; d < 64; d <<= 1) mx = fmaxf(mx, __shfl_xor(mx, d));
            float e0 = __expf(s0 - mx), e1 = __expf(s1 - mx);
            float ss = e0 + e1;
            for (int d = 1; d < 64; d <<= 1) ss += __shfl_xor(ss, d);
            float inv = 1.f / ss;
            encA[b * 392 + lane]      = (hf_t)((float)xh[b * 128 + lane] * e0 * inv);
            encA[b * 392 + 64 + lane] = (hf_t)((float)xh[b * 128 + 64 + lane] * e1 * inv);
        }
        __syncthreads();
        // (e) enc gates -> gbuf[o][4]
        {
            const h8* wv = (const h8*)(wb + W_EIF);
            h8 Ae[12];
#pragma unroll
            for (int ki = 0; ki < 12; ++ki)
                Ae[ki] = *(const h8*)(encA + fm * 392 + ki * 32 + fq * 8);
#pragma unroll
            for (int np = 0; np < 4; ++np) {
                const int nt = w * 4 + np;
                h8 Bf[12];
#pragma unroll
                for (int ki = 0; ki < 12; ++ki)
                    Bf[ki] = wv[(size_t)(nt * 12 + ki) * 64 + lane];
                f4 acc = {0.f, 0.f, 0.f, 0.f};
#pragma unroll
                for (int ki = 0; ki < 12; ++ki)
                    acc = __builtin_amdgcn_mfma_f32_16x16x32_f16(Ae[ki], Bf[ki], acc, 0, 0, 0);
                if (fq == 0) *(f4*)(gbuf + (nt * 16 + fm) * 4) = acc;
            }
        }
        __syncthreads();
        // (f) enc LSTM
        {
            const int b = tid >> 8, k = tid & 255;
            float gi = gbuf[k * 4 + b]           + bE[k];
            float gf = gbuf[(256 + k) * 4 + b]   + bE[256 + k];
            float gg = gbuf[(512 + k) * 4 + b]   + bE[512 + k];
            float go = gbuf[(768 + k) * 4 + b]   + bE[768 + k];
            float c2 = sigm(gf) * cfE[k * 4 + b] + sigm(gi) * tanh_f(gg);
            float h2 = sigm(go) * tanh_f(c2);
            cfE[k * 4 + b] = c2;
            attA[b * 648 + k]       = (hf_t)h2;
            attA[b * 648 + 256 + k] = (hf_t)c2;
            encA[b * 392 + 128 + k] = (hf_t)h2;
            midA[b * 520 + k]       = (hf_t)h2;
        }
        __syncthreads();
        // (g) mid gates
        {
            const h8* wv = (const h8*)(wb + W_MGF);
#pragma unroll
            for (int np = 0; np < 4; ++np) {
                const int nt = w * 4 + np;
                h8 Bf[16];
#pragma unroll
                for (int ki = 0; ki < 16; ++ki)
                    Bf[ki] = wv[(size_t)(nt * 16 + ki) * 64 + lane];
                f4 acc = {0.f, 0.f, 0.f, 0.f};
#pragma unroll
                for (int ki = 0; ki < 16; ++ki) {
                    h8 Af = *(const h8*)(midA + fm * 520 + ki * 32 + fq * 8);
                    acc = __builtin_amdgcn_mfma_f32_16x16x32_f16(Af, Bf[ki], acc, 0, 0, 0);
                }
                if (fq == 0) *(f4*)(gbuf + (nt * 16 + fm) * 4) = acc;
            }
        }
        __syncthreads();
        // (h) mid LSTM + store mid (L2-bypass)
        {
            const int b = tid >> 8, k = tid & 255;
            float gi = gbuf[k * 4 + b]           + bM[k];
            float gf = gbuf[(256 + k) * 4 + b]   + bM[256 + k];
            float gg = gbuf[(512 + k) * 4 + b]   + bM[512 + k];
            float go = gbuf[(768 + k) * 4 + b]   + bM[768 + k];
            float c2 = sigm(gf) * cfM[k * 4 + b] + sigm(gi) * tanh_f(gg);
            float h2 = sigm(go) * tanh_f(c2);
            cfM[k * 4 + b] = c2;
            midA[b * 520 + 256 + k] = (hf_t)h2;
            scs_u16((hf_t)h2, scrB + ((size_t)(b0 + b) * T_ + t) * H_ + k);
        }
        vm_drain();
        __syncthreads();
    }

    // ---------- Td pass: Td2[b][oc][t][e] = tanh(Ud.mid[b,t] + Udb) ----------
    {
        const h8* udf = (const h8*)(wb + W_UDF);
        for (int g = 0; g < 2; ++g) {
            const int mt = w + g * 16;                // 32 M-tiles of (b,t) rows
            const size_t arow = ((size_t)b0 * T_ + mt * 16 + fm) * H_;
            h8 A[8];
            scl8(scrB + arow + fq * 8, 64, A);
            for (int nt = 0; nt < 16; ++nt) {
                h8 Bf[8];
#pragma unroll
                for (int ki = 0; ki < 8; ++ki)
                    Bf[ki] = udf[(size_t)(nt * 8 + ki) * 64 + lane];
                f4 acc = {0.f, 0.f, 0.f, 0.f};
#pragma unroll
                for (int ki = 0; ki < 8; ++ki)
                    acc = __builtin_amdgcn_mfma_f32_16x16x32_f16(A[ki], Bf[ki], acc, 0, 0, 0);
                const int o = nt * 16 + fm;
                const float bv = Udb[o];
#pragma unroll
                for (int r = 0; r < 4; ++r) {
                    int row = mt * 16 + fq * 4 + r;
                    int bb2 = row >> 7, tt = row & 127;
                    scs_u16((hf_t)tanh_f(acc[r] + bv),
                            scrA + (size_t)(b0 + bb2) * 32768 + ((o >> 3) * 128 + tt) * 8 + (o & 7));
                }
            }
        }
    }
    vm_drain();
    __syncthreads();
    // zero decoder state: attA [h|c] rows 0-3, cfE, midA h-half rows 0-3
    for (int i = tid; i < 2048; i += TB) attA[(i >> 9) * 648 + (i & 511)] = (hf_t)0.f;
    for (int i = tid; i < 1024; i += TB) { cfE[i] = 0.f; midA[(i >> 8) * 520 + 256 + (i & 255)] = (hf_t)0.f; }
    __syncthreads();

    const float Vdb0 = Vdb[0];
    const float rb0  = rb[0];
    float* hful = cfM;   // decoder overlay [b][k] f32
    // ---------- Decoder ----------
    for (int s = 0; s < DS_; ++s) {
        // (a2) Wd GEMM -> Tah
        {
            const int nt = w;
            const h8* wv = (const h8*)(wb + W_WDF);
            h8 Bf[16];
#pragma unroll
            for (int ki = 0; ki < 16; ++ki)
                Bf[ki] = wv[(size_t)(nt * 16 + ki) * 64 + lane];
            f4 acc = {0.f, 0.f, 0.f, 0.f};
#pragma unroll
            for (int ki = 0; ki < 16; ++ki) {
                h8 Af = *(const h8*)(attA + fm * 648 + ki * 32 + fq * 8);
                acc = __builtin_amdgcn_mfma_f32_16x16x32_f16(Af, Bf[ki], acc, 0, 0, 0);
            }
            if (fq == 0) {
                const int k = nt * 16 + fm;
                float bv = bWD[k];
#pragma unroll
                for (int r = 0; r < 4; ++r)
                    Tah[r * 264 + k] = (hf_t)tanh_f(acc[r] + bv);
            }
        }
        __syncthreads();
        // (b2) temporal scores (no softmax), L2-bypass batched loads
        {
            const int b = tid >> 8, r = tid & 255, kh = r >> 7, j = r & 127;
            const hf_t* up = scrA + (size_t)(b0 + b) * 32768 + (size_t)kh * 16384 + (size_t)j * 8;
            float acc = 0.f;
#pragma unroll
            for (int g = 0; g < 2; ++g) {
                h8 u[8];
                scl8(up + (size_t)g * 8192, 2048, u);
#pragma unroll
                for (int i = 0; i < 8; ++i) {
                    const int kc = kh * 16 + g * 8 + i;
                    h8 ta = *(const h8*)(Tah + b * 264 + kc * 8);
                    h8 ve = *(const h8*)(vdsh + kc * 8);
#pragma unroll
                    for (int e = 0; e < 8; ++e) {
                        float tu = (float)u[i][e], taf = (float)ta[e];
                        acc = fmaf((float)ve[e] * (taf + tu),
                                   __builtin_amdgcn_rcpf(fmaf(taf, tu, 1.f)), acc);
                    }
                }
            }
            spart[tid] = acc;
        }
        __syncthreads();
        if (tid < 512) {
            const int b = tid >> 7, j = tid & 127;
            sbuf[b * 128 + j] = spart[b * 256 + j] + spart[b * 256 + 128 + j] + Vdb0;
        }
        __syncthreads();
        // (c2) dec_in[b,h] = sum_j t[b,j]*mid[b,j,h] : j-split batched dword loads
        {
            const int b = tid >> 8, r = tid & 255, jh = r >> 7, h2i = r & 127;
            const char* mp = (const char*)(scrB + ((size_t)(b0 + b) * T_ + jh * 64) * H_ + h2i * 2);
            float a0 = 0.f, a1 = 0.f;
#pragma unroll
            for (int g = 0; g < 8; ++g) {
                unsigned int dv[8];
                scl8d(mp + g * 8 * 512, 512, dv);
#pragma unroll
                for (int e = 0; e < 8; ++e) {
                    union { unsigned int u; _Float16 h[2]; } cv; cv.u = dv[e];
                    float wj = sbuf[b * 128 + jh * 64 + g * 8 + e];
                    a0 = fmaf(wj, (float)cv.h[0], a0);
                    a1 = fmaf(wj, (float)cv.h[1], a1);
                }
            }
            gbuf[tid * 2]     = a0;
            gbuf[tid * 2 + 1] = a1;
        }
        __syncthreads();
        {
            const int b = tid >> 8, r = tid & 255;
            if (r < 128) {
                float a0 = gbuf[tid * 2]     + gbuf[(tid + 128) * 2];
                float a1 = gbuf[tid * 2 + 1] + gbuf[(tid + 128) * 2 + 1];
                midA[b * 520 + r * 2]     = (hf_t)a0;
                midA[b * 520 + r * 2 + 1] = (hf_t)a1;
            }
        }
        __syncthreads();
        // (d2) dec gates
        {
            const h8* wv = (const h8*)(wb + W_DGF);
#pragma unroll
            for (int np = 0; np < 4; ++np) {
                const int nt = w * 4 + np;
                h8 Bf[16];
#pragma unroll
                for (int ki = 0; ki < 16; ++ki)
                    Bf[ki] = wv[(size_t)(nt * 16 + ki) * 64 + lane];
                f4 acc = {0.f, 0.f, 0.f, 0.f};
#pragma unroll
                for (int ki = 0; ki < 16; ++ki) {
                    h8 Af = *(const h8*)(midA + fm * 520 + ki * 32 + fq * 8);
                    acc = __builtin_amdgcn_mfma_f32_16x16x32_f16(Af, Bf[ki], acc, 0, 0, 0);
                }
                if (fq == 0) *(f4*)(gbuf + (nt * 16 + fm) * 4) = acc;
            }
        }
        __syncthreads();
        // (e2) dec LSTM
        {
            const int b = tid >> 8, k = tid & 255;
            float gi = gbuf[k * 4 + b]           + bD[k];
            float gf = gbuf[(256 + k) * 4 + b]   + bD[256 + k];
            float gg = gbuf[(512 + k) * 4 + b]   + bD[512 + k];
            float go = gbuf[(768 + k) * 4 + b]   + bD[768 + k];
            float c2 = sigm(gf) * cfE[k * 4 + b] + sigm(gi) * tanh_f(gg);
            float h2 = sigm(go) * tanh_f(c2);
            cfE[k * 4 + b] = c2;
            attA[b * 648 + k]       = (hf_t)h2;
            attA[b * 648 + 256 + k] = (hf_t)c2;
            midA[b * 520 + 256 + k] = (hf_t)h2;
            hful[b * 256 + k] = h2;
        }
        __syncthreads();
        // (f2) out[b, s-6] = rW.h + rb
        if (s >= 6 && tid < 128) {
            const int b = tid >> 5, l = tid & 31;
            float p = 0.f;
#pragma unroll
            for (int i = 0; i < 8; ++i)
                p = fmaf(rW[l + i * 32], hful[b * 256 + l + i * 32], p);
            for (int d = 1; d < 32; d <<= 1) p += __shfl_xor(p, d);
            if (l == 0) out[(size_t)(b0 + b) * TD_ + (s - 6)] = p + rb0;
        }
        __syncthreads();
    }
}

extern "C" void kernel_launch(void* const* d_in, const int* in_sizes, int n_in,
                              void* d_out, int out_size, void* d_ws, size_t ws_size,
                              hipStream_t stream) {
    const float* inp  = (const float*)d_in[0];
    const float* UeW  = (const float*)d_in[2];
    const float* Ueb  = (const float*)d_in[3];
    const float* Ue2W = (const float*)d_in[4];
    const float* Ue2b = (const float*)d_in[5];
    const float* WeW  = (const float*)d_in[6];
    const float* Web  = (const float*)d_in[7];
    const float* VeW  = (const float*)d_in[8];
    const float* Veb  = (const float*)d_in[9];
    const float* UdW  = (const float*)d_in[10];
    const float* Udb  = (const float*)d_in[11];
    const float* WdW  = (const float*)d_in[12];
    const float* Wdb  = (const float*)d_in[13];
    const float* VdW  = (const float*)d_in[14];
    const float* Vdb  = (const float*)d_in[15];
    const float* eWih = (const float*)d_in[16];
    const float* eWhh = (const float*)d_in[17];
    const float* ebih = (const float*)d_in[18];
    const float* ebhh = (const float*)d_in[19];
    const float* mWih = (const float*)d_in[20];
    const float* mWhh = (const float*)d_in[21];
    const float* mbih = (const float*)d_in[22];
    const float* mbhh = (const float*)d_in[23];
    const float* dWih = (const float*)d_in[24];
    const float* dWhh = (const float*)d_in[25];
    const float* dbih = (const float*)d_in[26];
    const float* dbhh = (const float*)d_in[27];
    const float* rW   = (const float*)d_in[28];
    const float* rb   = (const float*)d_in[29];

    hf_t* wsb  = (hf_t*)d_ws;
    hf_t* scrA = wsb + SCR_A;
    hf_t* scrB = wsb + SCR_B;

    hipFuncSetAttribute((const void*)dsrnn_kernel,
                        hipFuncAttributeMaxDynamicSharedMemorySize, LDS_BYTES);

    convw_kernel<<<512, 256, 0, stream>>>(WeW, Ue2W, eWih, eWhh, mWih, mWhh,
                                          dWih, dWhh, WdW, UdW, UeW, wsb);

    dsrnn_kernel<<<B_ / BB, TB, LDS_BYTES, stream>>>(
        inp, Ueb, Ue2b, Web, VeW, Veb, Udb, Wdb, VdW, Vdb,
        ebih, ebhh, mbih, mbhh, dbih, dbhh, rW, rb,
        wsb, scrA, scrB, (float*)d_out);
}